// Round 15
// baseline (598.377 us; speedup 1.0000x reference)
//
#include <hip/hip_runtime.h>
#include <hip/hip_fp16.h>

// MPNN on MI355X.
//
// Algebra: msg layer-1 is linear before its relu:
//   m1 = relu(P[dst] + Q[src] + ea@W1e + b1), P = h@W1[0:64]+b1, Q = h@W1[64:128]
// R3: m2 GEMM via MFMA. R4: dst-sorted CSR, consumer-side aggregation.
// R5-R7: flat 32-edge batches, readlane metadata, ballot segment mask,
//     per-segment coalesced atomic. R12: fragment-layout weights.
// R17 (WIN, 642us): k_edge weight B-frags -> block-shared LDS. 87->67us.
// R20-R25 (all null/neg): TLP raise, cache shaping x2, reg-staging,
//     gload_lds stage, in-place swizzle stage. Latency restructures dead.
// R26-R28 (WIN, 561.8us): fp16x2 packed m1 (P/Q/m1/W2 fp16, v_pk ops,
//     f16 MFMA). R27's ds_bpermute fixed via readlane-pair + cndmask.
// R29 (WIN, 552.2us): k_scatter 32B packed records (2xfloat4/edge) killed
//     the 5x write amplification; k_scatter below top-5 cutoff.
// R30: profile now shows k_upd2 = 51.4us x4 = 37% of total, VALU 3%,
//     occ 9.3% — latency-bound at 1.53 blocks/CU (NB_T=392). The old
//     "1-tile/wave node grids lose" note was never a clean single-variable
//     measurement (bundled reverts, R18 coupling). Single-variable retest:
//     NB_T 392 -> 784 (3.06 blocks/CU, ~1 tile/wave, 2x TLP on kernels
//     that are ~90% stalled). Everything else byte-identical to R29.

typedef __attribute__((ext_vector_type(8))) short short8;
typedef __attribute__((ext_vector_type(4))) float float4v;

__device__ __forceinline__ unsigned short f2bf(float f) {
    unsigned int u = __float_as_uint(f);
    unsigned int r = u + 0x7fff + ((u >> 16) & 1);   // RTNE
    return (unsigned short)(r >> 16);
}
__device__ __forceinline__ float bf2f(unsigned short u) {
    return __uint_as_float(((unsigned int)u) << 16);
}
__device__ __forceinline__ __half2 u2h2(unsigned int u) {
    union { unsigned int u; __half2 h; } c; c.u = u; return c.h;
}
__device__ __forceinline__ unsigned int h22u(__half2 h) {
    union { unsigned int u; __half2 h; } c; c.h = h; return c.u;
}
// ROCm 7.2 lacks __hmax2; gfx950 has v_pk_max_f16 — emit it directly.
__device__ __forceinline__ unsigned int pkmax0(unsigned int a) {
    unsigned int r;
    asm("v_pk_max_f16 %0, %1, %2" : "=v"(r) : "v"(a), "v"(0u));
    return r;
}

#define MFMA16(a, b, c)  __builtin_amdgcn_mfma_f32_16x16x32_bf16(a, b, c, 0, 0, 0)
#define MFMA16H(a, b, c) __builtin_amdgcn_mfma_f32_16x16x32_f16(a, b, c, 0, 0, 0)

struct bfpair { short hi, lo; };
__device__ __forceinline__ bfpair wsplit(float wv) {
    bfpair p;
    unsigned short h = f2bf(wv);
    float hf = __uint_as_float(((unsigned int)h) << 16);
    p.hi = (short)h;
    p.lo = (short)f2bf(wv - hf);
    return p;
}

// fragment-layout weight prep offsets (ushort elements)
#define WP_TOTAL 106496
#define OFF_IN   0
#define OFF_PRE(l)  (8192  + (l) * 8192)
#define OFF_MW2(l)  (40960 + (l) * 4096)
#define OFF_UW1(l)  (57344 + (l) * 8192)
#define OFF_UW2(l)  (90112 + (l) * 4096)

// ---------------- weight prep: fp32 -> hi/lo bf16 (fp16 for MW2) ----------------
__global__ __launch_bounds__(256) void k_wprep(const float* __restrict__ lin_w,
        const float* __restrict__ mw1, const float* __restrict__ mw2,
        const float* __restrict__ uw1, const float* __restrict__ uw2,
        unsigned short* __restrict__ H, unsigned short* __restrict__ L) {
    const int tid = blockIdx.x * 256 + threadIdx.x;
    if (tid >= WP_TOTAL) return;
    float val;
    if (tid < 8192) {                                  // lin_in_w: KF=4, NT=4
        int rem = tid;
        int nt = rem >> 11, kf = (rem >> 9) & 3;
        int lane = (rem >> 3) & 63, j = rem & 7;
        int k = kf * 32 + (lane >> 4) * 8 + j;
        val = lin_w[k * 64 + nt * 16 + (lane & 15)];
    } else if (tid < 40960) {                          // msg_w1[0:128]: KF=2, NT=8
        int t = tid - 8192, layer = t >> 13, rem = t & 8191;
        int nt = rem >> 10, kf = (rem >> 9) & 1;
        int lane = (rem >> 3) & 63, j = rem & 7;
        int k = kf * 32 + (lane >> 4) * 8 + j;
        const float* w1 = mw1 + (size_t)layer * 134 * 64;
        val = (nt < 4) ? w1[k * 64 + nt * 16 + (lane & 15)]
                       : w1[(64 + k) * 64 + (nt - 4) * 16 + (lane & 15)];
    } else if (tid < 57344) {                          // msg_w2: KF=2, NT=4 (fp16!)
        int t = tid - 40960, layer = t >> 12, rem = t & 4095;
        int nt = rem >> 10, kf = (rem >> 9) & 1;
        int lane = (rem >> 3) & 63, j = rem & 7;
        int k = kf * 32 + (lane >> 4) * 8 + j;
        val = mw2[(size_t)layer * 4096 + k * 64 + nt * 16 + (lane & 15)];
    } else if (tid < 90112) {                          // upd_w1: KF=4, NT=4
        int t = tid - 57344, layer = t >> 13, rem = t & 8191;
        int nt = rem >> 11, kf = (rem >> 9) & 3;
        int lane = (rem >> 3) & 63, j = rem & 7;
        int k = kf * 32 + (lane >> 4) * 8 + j;
        val = uw1[(size_t)layer * 8192 + k * 64 + nt * 16 + (lane & 15)];
    } else {                                           // upd_w2: KF=2, NT=4
        int t = tid - 90112, layer = t >> 12, rem = t & 4095;
        int nt = rem >> 10, kf = (rem >> 9) & 1;
        int lane = (rem >> 3) & 63, j = rem & 7;
        int k = kf * 32 + (lane >> 4) * 8 + j;
        val = uw2[(size_t)layer * 4096 + k * 64 + nt * 16 + (lane & 15)];
    }
    if (tid >= 40960 && tid < 57344) {                 // fp16 hi/lo for k_edge m2
        __half hh = __float2half_rn(val);
        float hf = __half2float(hh);
        __half hl = __float2half_rn(val - hf);
        H[tid] = __half_as_ushort(hh);
        L[tid] = __half_as_ushort(hl);
    } else {
        bfpair p = wsplit(val);
        H[tid] = (unsigned short)p.hi;
        L[tid] = (unsigned short)p.lo;
    }
}

#define LOADFRAG(dst, arr, nt, KF, kf) \
    dst = *(const short8*)&arr[((((nt) * (KF)) + (kf)) * 64 + lane) * 8]

// ---------------- CSR build (dst bins) ----------------
__global__ __launch_bounds__(256) void k_hist(const int* __restrict__ dst,
        int* __restrict__ deg, int nEdges) {
    int e = blockIdx.x * blockDim.x + threadIdx.x;
    if (e < nEdges) atomicAdd(&deg[dst[e]], 1);
}

__global__ __launch_bounds__(256) void k_scan1(const int* __restrict__ deg,
        int* __restrict__ local, int* __restrict__ bsum, int nNodes) {
    __shared__ int sm[256];
    const int t = threadIdx.x;
    const int n = blockIdx.x * 256 + t;
    int v = (n < nNodes) ? deg[n] : 0;
    sm[t] = v;
    __syncthreads();
    for (int off = 1; off < 256; off <<= 1) {
        int u = (t >= off) ? sm[t - off] : 0;
        __syncthreads();
        sm[t] += u;
        __syncthreads();
    }
    if (n < nNodes) local[n] = sm[t] - v;
    if (t == 255) bsum[blockIdx.x] = sm[255];
}

__global__ __launch_bounds__(256) void k_scan2(int* __restrict__ bsum, int nB) {
    __shared__ int sm[256];
    const int t = threadIdx.x;
    int v = (t < nB) ? bsum[t] : 0;
    sm[t] = v;
    __syncthreads();
    for (int off = 1; off < 256; off <<= 1) {
        int u = (t >= off) ? sm[t - off] : 0;
        __syncthreads();
        sm[t] += u;
        __syncthreads();
    }
    if (t < nB) bsum[t] = sm[t] - v;
}

__global__ __launch_bounds__(256) void k_scan3(const int* __restrict__ local,
        const int* __restrict__ bsum, int* __restrict__ cursor, int nNodes) {
    int n = blockIdx.x * 256 + threadIdx.x;
    if (n < nNodes) cursor[n] = bsum[blockIdx.x] + local[n];
}

// R29: one 32B packed record per edge: {src, dst, ea[0..5]}, 2x float4.
__global__ __launch_bounds__(256) void k_scatter(const int* __restrict__ src,
        const int* __restrict__ dst, const float* __restrict__ ea,
        int* __restrict__ cursor, float* __restrict__ rec, int nEdges) {
    int e = blockIdx.x * blockDim.x + threadIdx.x;
    if (e < nEdges) {
        int d = dst[e];
        int s = src[e];
        int pos = atomicAdd(&cursor[d], 1);
        const float* p = ea + (size_t)e * 6;
        float4 lo, hi;
        lo.x = __int_as_float(s);
        lo.y = __int_as_float(d);
        lo.z = p[0];
        lo.w = p[1];
        hi.x = p[2];
        hi.y = p[3];
        hi.z = p[4];
        hi.w = p[5];
        float4* q = (float4*)(rec + (size_t)pos * 8);
        q[0] = lo;
        q[1] = hi;
    }
}

// ---------------- node-side MFMA GEMM kernels (R15-exact) ----------------
// A-frag: A[m=col][k=quad*8+j]; C: col=lane&15, row=quad*4+reg (verified).

// h = x @ Win + b   (K=128, N=64)
__global__ __launch_bounds__(256) void k_in(const float* __restrict__ x,
        const unsigned short* __restrict__ wh, const unsigned short* __restrict__ wl,
        const float* __restrict__ bia, float* __restrict__ h, int nNodes) {
    const int lane = threadIdx.x & 63;
    const int wib  = threadIdx.x >> 6;
    const int quad = lane >> 4, col = lane & 15;
    __shared__ unsigned short sm[4][16 * 136];
    unsigned short* __restrict__ mt = sm[wib];

    short8 bh[4][4], bl[4][4];
#pragma unroll
    for (int nt = 0; nt < 4; ++nt)
#pragma unroll
        for (int kf = 0; kf < 4; ++kf) {
            LOADFRAG(bh[nt][kf], wh, nt, 4, kf);
            LOADFRAG(bl[nt][kf], wl, nt, 4, kf);
        }
    float bv[4];
#pragma unroll
    for (int nt = 0; nt < 4; ++nt) bv[nt] = bia[nt * 16 + col];

    const int nTiles = (nNodes + 15) >> 4;
    const int wid = blockIdx.x * 4 + wib;
    const int nw  = gridDim.x * 4;
    for (int tile = wid; tile < nTiles; tile += nw) {
        const int base = tile * 16;
#pragma unroll
        for (int j = 0; j < 16; ++j) {
            int row = min(base + j, nNodes - 1);
            mt[j * 136 + lane]      = f2bf(x[(size_t)row * 128 + lane]);
            mt[j * 136 + 64 + lane] = f2bf(x[(size_t)row * 128 + 64 + lane]);
        }
        __builtin_amdgcn_s_waitcnt(0);
        short8 a[4];
#pragma unroll
        for (int kf = 0; kf < 4; ++kf)
            a[kf] = *(const short8*)&mt[col * 136 + kf * 32 + quad * 8];
#pragma unroll
        for (int nt = 0; nt < 4; ++nt) {
            float4v c = {0.f, 0.f, 0.f, 0.f};
#pragma unroll
            for (int kf = 0; kf < 4; ++kf) c = MFMA16(a[kf], bh[nt][kf], c);
#pragma unroll
            for (int kf = 0; kf < 4; ++kf) c = MFMA16(a[kf], bl[nt][kf], c);
#pragma unroll
            for (int r = 0; r < 4; ++r) {
                int row = base + quad * 4 + r;
                if (row < nNodes)
                    h[(size_t)row * 64 + nt * 16 + col] = c[r] + bv[nt];
            }
        }
    }
}

// [P|Q] = h @ [W1[0:64] | W1[64:128]]; P += b1   (K=64, N=128), FP16 outputs
__global__ __launch_bounds__(256) void k_pre(const float* __restrict__ h,
        const unsigned short* __restrict__ wh, const unsigned short* __restrict__ wl,
        const float* __restrict__ b1m,
        unsigned short* __restrict__ P, unsigned short* __restrict__ Q,
        int nNodes) {
    const int lane = threadIdx.x & 63;
    const int wib  = threadIdx.x >> 6;
    const int quad = lane >> 4, col = lane & 15;
    __shared__ unsigned short sm[4][16 * 72];
    unsigned short* __restrict__ mt = sm[wib];

    short8 bh[8][2], bl[8][2];
#pragma unroll
    for (int nt = 0; nt < 8; ++nt)
#pragma unroll
        for (int kf = 0; kf < 2; ++kf) {
            LOADFRAG(bh[nt][kf], wh, nt, 2, kf);
            LOADFRAG(bl[nt][kf], wl, nt, 2, kf);
        }
    float bv1[4];
#pragma unroll
    for (int nt = 0; nt < 4; ++nt) bv1[nt] = b1m[nt * 16 + col];

    const int nTiles = (nNodes + 15) >> 4;
    const int wid = blockIdx.x * 4 + wib;
    const int nw  = gridDim.x * 4;
    for (int tile = wid; tile < nTiles; tile += nw) {
        const int base = tile * 16;
#pragma unroll
        for (int j = 0; j < 16; ++j) {
            int row = min(base + j, nNodes - 1);
            mt[j * 72 + lane] = f2bf(h[(size_t)row * 64 + lane]);
        }
        __builtin_amdgcn_s_waitcnt(0);
        short8 a0 = *(const short8*)&mt[col * 72 + quad * 8];
        short8 a1 = *(const short8*)&mt[col * 72 + 32 + quad * 8];
#pragma unroll
        for (int nt = 0; nt < 8; ++nt) {
            float4v c = {0.f, 0.f, 0.f, 0.f};
            c = MFMA16(a0, bh[nt][0], c);
            c = MFMA16(a1, bh[nt][1], c);
            c = MFMA16(a0, bl[nt][0], c);
            c = MFMA16(a1, bl[nt][1], c);
            unsigned short* __restrict__ outp = (nt < 4) ? P : Q;
            const int nc = (nt & 3) * 16 + col;
            const float badd = (nt < 4) ? bv1[nt & 3] : 0.f;
#pragma unroll
            for (int r = 0; r < 4; ++r) {
                int row = base + quad * 4 + r;
                if (row < nNodes)
                    outp[(size_t)row * 64 + nc] =
                        __half_as_ushort(__float2half_rn(c[r] + badd));
            }
        }
    }
}

// tv = relu([h|agg] @ U1 + b1)   (K=128, N=64); tv aliases agg (in-place)
__global__ __launch_bounds__(256) void k_upd1(const float* __restrict__ h,
        const float* __restrict__ agg,
        const unsigned short* __restrict__ wh, const unsigned short* __restrict__ wl,
        const float* __restrict__ b1, float* __restrict__ tv, int nNodes) {
    const int lane = threadIdx.x & 63;
    const int wib  = threadIdx.x >> 6;
    const int quad = lane >> 4, col = lane & 15;
    __shared__ unsigned short sm[4][16 * 136];
    unsigned short* __restrict__ mt = sm[wib];

    short8 bh[4][4], bl[4][4];
#pragma unroll
    for (int nt = 0; nt < 4; ++nt)
#pragma unroll
        for (int kf = 0; kf < 4; ++kf) {
            LOADFRAG(bh[nt][kf], wh, nt, 4, kf);
            LOADFRAG(bl[nt][kf], wl, nt, 4, kf);
        }
    float bv[4];
#pragma unroll
    for (int nt = 0; nt < 4; ++nt) bv[nt] = b1[nt * 16 + col];

    const int nTiles = (nNodes + 15) >> 4;
    const int wid = blockIdx.x * 4 + wib;
    const int nw  = gridDim.x * 4;
    for (int tile = wid; tile < nTiles; tile += nw) {
        const int base = tile * 16;
#pragma unroll
        for (int j = 0; j < 16; ++j) {
            int row = min(base + j, nNodes - 1);
            mt[j * 136 + lane]      = f2bf(h[(size_t)row * 64 + lane]);
            mt[j * 136 + 64 + lane] = f2bf(agg[(size_t)row * 64 + lane]);
        }
        __builtin_amdgcn_s_waitcnt(0);
        short8 a[4];
#pragma unroll
        for (int kf = 0; kf < 4; ++kf)
            a[kf] = *(const short8*)&mt[col * 136 + kf * 32 + quad * 8];
#pragma unroll
        for (int nt = 0; nt < 4; ++nt) {
            float4v c = {0.f, 0.f, 0.f, 0.f};
#pragma unroll
            for (int kf = 0; kf < 4; ++kf) c = MFMA16(a[kf], bh[nt][kf], c);
#pragma unroll
            for (int kf = 0; kf < 4; ++kf) c = MFMA16(a[kf], bl[nt][kf], c);
#pragma unroll
            for (int r = 0; r < 4; ++r) {
                int row = base + quad * 4 + r;
                if (row < nNodes)
                    tv[(size_t)row * 64 + nt * 16 + col] = fmaxf(c[r] + bv[nt], 0.f);
            }
        }
    }
}

// h += relu(tv @ U2 + b2); zero tv(=agg) for next layer; optional colsum
__global__ __launch_bounds__(256) void k_upd2(float* __restrict__ h,
        float* __restrict__ tv,
        const unsigned short* __restrict__ wh, const unsigned short* __restrict__ wl,
        const float* __restrict__ b2, float* __restrict__ colsum,
        int nNodes, int doCS) {
    const int lane = threadIdx.x & 63;
    const int wib  = threadIdx.x >> 6;
    const int quad = lane >> 4, col = lane & 15;
    __shared__ unsigned short sm[4][16 * 72];
    unsigned short* __restrict__ mt = sm[wib];

    short8 bh[4][2], bl[4][2];
#pragma unroll
    for (int nt = 0; nt < 4; ++nt)
#pragma unroll
        for (int kf = 0; kf < 2; ++kf) {
            LOADFRAG(bh[nt][kf], wh, nt, 2, kf);
            LOADFRAG(bl[nt][kf], wl, nt, 2, kf);
        }
    float bv[4];
#pragma unroll
    for (int nt = 0; nt < 4; ++nt) bv[nt] = b2[nt * 16 + col];

    float cs0 = 0.f, cs1 = 0.f, cs2 = 0.f, cs3 = 0.f;
    const int nTiles = (nNodes + 15) >> 4;
    const int wid = blockIdx.x * 4 + wib;
    const int nw  = gridDim.x * 4;
    for (int tile = wid; tile < nTiles; tile += nw) {
        const int base = tile * 16;
#pragma unroll
        for (int j = 0; j < 16; ++j) {
            int row = min(base + j, nNodes - 1);
            mt[j * 72 + lane] = f2bf(tv[(size_t)row * 64 + lane]);
        }
        __builtin_amdgcn_s_waitcnt(0);   // drains vmcnt too -> safe to zero tv
#pragma unroll
        for (int j = 0; j < 16; ++j) {
            int row = base + j;
            if (row < nNodes) tv[(size_t)row * 64 + lane] = 0.f;
        }
        short8 a0 = *(const short8*)&mt[col * 72 + quad * 8];
        short8 a1 = *(const short8*)&mt[col * 72 + 32 + quad * 8];
#pragma unroll
        for (int nt = 0; nt < 4; ++nt) {
            float4v c = {0.f, 0.f, 0.f, 0.f};
            c = MFMA16(a0, bh[nt][0], c);
            c = MFMA16(a1, bh[nt][1], c);
            c = MFMA16(a0, bl[nt][0], c);
            c = MFMA16(a1, bl[nt][1], c);
#pragma unroll
            for (int r = 0; r < 4; ++r) {
                int row = base + quad * 4 + r;
                if (row < nNodes) {
                    float* hp = &h[(size_t)row * 64 + nt * 16 + col];
                    float hn = *hp + fmaxf(c[r] + bv[nt], 0.f);
                    *hp = hn;
                    cs0 += (nt == 0) ? hn : 0.f;
                    cs1 += (nt == 1) ? hn : 0.f;
                    cs2 += (nt == 2) ? hn : 0.f;
                    cs3 += (nt == 3) ? hn : 0.f;
                }
            }
        }
    }
    if (doCS) {
        cs0 += __shfl_xor(cs0, 16); cs0 += __shfl_xor(cs0, 32);
        cs1 += __shfl_xor(cs1, 16); cs1 += __shfl_xor(cs1, 32);
        cs2 += __shfl_xor(cs2, 16); cs2 += __shfl_xor(cs2, 32);
        cs3 += __shfl_xor(cs3, 16); cs3 += __shfl_xor(cs3, 32);
        const float tot = (quad == 0) ? cs0 : (quad == 1) ? cs1
                        : (quad == 2) ? cs2 : cs3;
        atomicAdd(&colsum[lane], tot);   // lane == quad*16+col
    }
}

// ---------------- edge kernel: fp16x2 packed m1, 32-edge batches ----------------
// R17: W2 hi/lo B-frags in block-shared LDS (fp16): hi ushort 0, lo 4096.
// R26-R28: m1 loop = 16 iters x 2 rows (half-wave/row) with v_pk_f16 ops;
//      row metadata via readlane-pair + cndmask (NO bpermute).
// R29: edge data from 32B packed records; ea table = 4 coalesced dword
//      loads of the record block (256 entries; int slots never read).
#define EST 72   // fp16 elems per staged m1 row (144B stride, bank-spread)

__global__ __launch_bounds__(256, 4) void k_edge(const unsigned short* __restrict__ P,
        const unsigned short* __restrict__ Q, const float* __restrict__ rec,
        const float* __restrict__ w1e,
        const unsigned short* __restrict__ wh, const unsigned short* __restrict__ wl,
        const float* __restrict__ b2,
        float* __restrict__ agg, int nEdges) {
    const int lane = threadIdx.x & 63;
    const int wib  = threadIdx.x >> 6;
    const int wid  = blockIdx.x * 4 + wib;
    const int nw   = gridDim.x * 4;
    const int quad = lane >> 4;
    const int col  = lane & 15;
    const int li   = lane & 31;
    const int hs   = lane >> 5;          // half-wave select (0/1)

    __shared__ unsigned short m1b[4][32 * EST];   // 18432 B (fp16 m1)
    __shared__ unsigned int   eab[4][256];        //  4096 B (half2-bcast rec block)
    __shared__ unsigned short wB[8192];           // 16384 B: [hi | lo] fp16 frags
    unsigned short* __restrict__ mt  = m1b[wib];
    unsigned int*   __restrict__ eaw = eab[wib];

    // block-cooperative weight stage: 8 frags hi + 8 frags lo = 1024 short8
    {
        const short8* __restrict__ sH = (const short8*)wh;
        const short8* __restrict__ sL = (const short8*)wl;
        short8* __restrict__ dB = (short8*)wB;
        for (int i = threadIdx.x; i < 512; i += 256) {
            dB[i]       = sH[i];
            dB[512 + i] = sL[i];
        }
    }
    __syncthreads();

    // W1e column-pair weights as half2 (cols 2li, 2li+1)
    __half2 w1ec2[6];
#pragma unroll
    for (int jj = 0; jj < 6; ++jj)
        w1ec2[jj] = __halves2half2(__float2half_rn(w1e[jj * 64 + 2 * li]),
                                   __float2half_rn(w1e[jj * 64 + 2 * li + 1]));

    float b2v[4];
#pragma unroll
    for (int nt = 0; nt < 4; ++nt) b2v[nt] = b2[nt * 16 + col];

    // contiguous chunk per wave: dst-sorted records -> P/agg locality
    const int nBatch = (nEdges + 31) >> 5;
    const int per = nBatch / nw, rem = nBatch % nw;
    const int btLo = wid * per + min(wid, rem);
    const int btHi = btLo + per + (wid < rem ? 1 : 0);

    const int* __restrict__ reci = (const int*)rec;

    for (int bt = btLo; bt < btHi; ++bt) {
        const int base = __builtin_amdgcn_readfirstlane(bt << 5);
        const int gidx = min(base + li, nEdges - 1);
        const int vsj = reci[(size_t)gidx * 8];       // row li's src
        const int vdj = reci[(size_t)gidx * 8 + 1];   // row li's dst (lanes 32-63 dup)
        const int vprev = __shfl_up(vdj, 1);
        unsigned long long bmask =
            __ballot(lane < 32 && (li == 0 || vdj != vprev));
        bmask |= (1ull << 32) | 1ull;

        // ---- record block -> half2-broadcast LDS table (4 coalesced loads) ----
        const int fMax = nEdges * 8 - 1;
        const int fBase = base * 8;
#pragma unroll
        for (int k = 0; k < 4; ++k)
            eaw[k * 64 + lane] =
                h22u(__float2half2_rn(rec[min(fBase + k * 64 + lane, fMax)]));

        // ---- m1: 16 iters x 2 rows, fp16x2 column pairs ----
        // row select via readlane-pair (compile-time lanes) + cndmask.
#pragma unroll
        for (int j = 0; j < 16; ++j) {
            const int d0 = __builtin_amdgcn_readlane(vdj, 2 * j);
            const int d1 = __builtin_amdgcn_readlane(vdj, 2 * j + 1);
            const int s0 = __builtin_amdgcn_readlane(vsj, 2 * j);
            const int s1 = __builtin_amdgcn_readlane(vsj, 2 * j + 1);
            const int d = hs ? d1 : d0;
            const int s = hs ? s1 : s0;
            const int rsel = 2 * j + hs;               // this half-wave's row
            const unsigned int p2 = *(const unsigned int*)&P[(size_t)d * 64 + 2 * li];
            const unsigned int q2 = *(const unsigned int*)&Q[(size_t)s * 64 + 2 * li];
            __half2 t = __hadd2(u2h2(p2), u2h2(q2));
#pragma unroll
            for (int jj = 0; jj < 6; ++jj) {
                // record rsel, float slot 2+jj -> table index rsel*8 + 2 + jj
                const unsigned int eu = eaw[16 * j + 8 * hs + 2 + jj];
                t = __hfma2(u2h2(eu), w1ec2[jj], t);
            }
            *(unsigned int*)((char*)mt + rsel * (EST * 2) + li * 4) = pkmax0(h22u(t));
        }
        __builtin_amdgcn_s_waitcnt(0);   // wave-local LDS drain

        short8 a00 = *(const short8*)&mt[col * EST + quad * 8];
        short8 a01 = *(const short8*)&mt[col * EST + 32 + quad * 8];
        short8 a10 = *(const short8*)&mt[(16 + col) * EST + quad * 8];
        short8 a11 = *(const short8*)&mt[(16 + col) * EST + 32 + quad * 8];

        // m2 (fp16 MFMA, same frag layout) for both 16-row tiles
        float4v m2v[2][4];
#pragma unroll
        for (int nt = 0; nt < 4; ++nt) {
            const short8 h0 = *(const short8*)&wB[((nt * 2 + 0) * 64 + lane) * 8];
            const short8 h1 = *(const short8*)&wB[((nt * 2 + 1) * 64 + lane) * 8];
            const short8 l0 = *(const short8*)&wB[4096 + ((nt * 2 + 0) * 64 + lane) * 8];
            const short8 l1 = *(const short8*)&wB[4096 + ((nt * 2 + 1) * 64 + lane) * 8];
            float4v c0 = {0.f, 0.f, 0.f, 0.f};
            float4v c1 = {0.f, 0.f, 0.f, 0.f};
            c0 = MFMA16H(a00, h0, c0);
            c0 = MFMA16H(a01, h1, c0);
            c0 = MFMA16H(a00, l0, c0);
            c0 = MFMA16H(a01, l1, c0);
            c1 = MFMA16H(a10, h0, c1);
            c1 = MFMA16H(a11, h1, c1);
            c1 = MFMA16H(a10, l0, c1);
            c1 = MFMA16H(a11, l1, c1);
#pragma unroll
            for (int r = 0; r < 4; ++r) {
                const bool v0 = base + (quad * 4 + r) < nEdges;
                const bool v1 = base + 16 + (quad * 4 + r) < nEdges;
                m2v[0][nt][r] = v0 ? fmaxf(c0[r] + b2v[nt], 0.f) : 0.f;
                m2v[1][nt][r] = v1 ? fmaxf(c1[r] + b2v[nt], 0.f) : 0.f;
            }
        }

        // ---- segmented reduce + one coalesced atomic per segment ----
        int r0 = 0;
        while (r0 < 32) {
            const int nid = __builtin_amdgcn_readlane(vdj, r0);
            const int r1 = r0 + 1 + (int)__builtin_ctzll(bmask >> (r0 + 1));
            float s0 = 0.f, s1 = 0.f, s2 = 0.f, s3 = 0.f;
#pragma unroll
            for (int t = 0; t < 2; ++t)
#pragma unroll
                for (int r = 0; r < 4; ++r) {
                    const int R = t * 16 + quad * 4 + r;
                    const bool in = (R >= r0) && (R < r1);
                    s0 += in ? m2v[t][0][r] : 0.f;
                    s1 += in ? m2v[t][1][r] : 0.f;
                    s2 += in ? m2v[t][2][r] : 0.f;
                    s3 += in ? m2v[t][3][r] : 0.f;
                }
            s0 += __shfl_xor(s0, 16); s0 += __shfl_xor(s0, 32);
            s1 += __shfl_xor(s1, 16); s1 += __shfl_xor(s1, 32);
            s2 += __shfl_xor(s2, 16); s2 += __shfl_xor(s2, 32);
            s3 += __shfl_xor(s3, 16); s3 += __shfl_xor(s3, 32);
            const float tot = (quad == 0) ? s0 : (quad == 1) ? s1
                            : (quad == 2) ? s2 : s3;
            atomicAdd(&agg[(size_t)nid * 64 + lane], tot);
            r0 = r1;
        }
    }
}

__global__ void k_out(const float* __restrict__ colsum, const float* __restrict__ pw,
                      const float* __restrict__ pb, float* __restrict__ out, int nNodes) {
    const int lane = threadIdx.x;
    float v = colsum[lane] * pw[lane];
#pragma unroll
    for (int off = 32; off; off >>= 1) v += __shfl_down(v, off);
    if (lane == 0) out[0] = v + (float)nNodes * pb[0];
}

extern "C" void kernel_launch(void* const* d_in, const int* in_sizes, int n_in,
                              void* d_out, int out_size, void* d_ws, size_t ws_size,
                              hipStream_t stream) {
    const float* x     = (const float*)d_in[0];
    const int*   ei    = (const int*)d_in[1];
    const float* ea    = (const float*)d_in[2];
    const float* lin_w = (const float*)d_in[3];
    const float* lin_b = (const float*)d_in[4];
    const float* mw1   = (const float*)d_in[5];
    const float* mb1   = (const float*)d_in[6];
    const float* mw2   = (const float*)d_in[7];
    const float* mb2   = (const float*)d_in[8];
    const float* uw1   = (const float*)d_in[9];
    const float* ub1   = (const float*)d_in[10];
    const float* uw2   = (const float*)d_in[11];
    const float* ub2   = (const float*)d_in[12];
    const float* pw    = (const float*)d_in[13];
    const float* pb    = (const float*)d_in[14];

    const int nNodes = in_sizes[0] / 128;
    const int nEdges = in_sizes[1] / 2;
    const int* src = ei;            // edge_index[0]
    const int* dst = ei + nEdges;   // edge_index[1]

    // workspace layout (floats, then ushorts, then ints)
    float* h       = (float*)d_ws;
    float* agg     = h   + (size_t)nNodes * 64;   // also tv (in-place upd1)
    float* rec     = agg + (size_t)nNodes * 64;   // 32B packed edge records
    float* colsum  = rec + (size_t)nEdges * 8;
    unsigned short* Pb  = (unsigned short*)(colsum + 64);
    unsigned short* Qb  = Pb + (size_t)nNodes * 64;
    unsigned short* wpH = Qb + (size_t)nNodes * 64;
    unsigned short* wpL = wpH + WP_TOTAL;
    int*   deg     = (int*)(wpL + WP_TOTAL);
    int*   cursor  = deg + nNodes;
    int*   local   = cursor + nNodes;
    int*   bsum    = local + nNodes;

    const int NB_T    = 784;                     // R30: 3 blocks/CU, ~1 tile/wave
    const int NB_EDGE = 2048;
    const int NB_FLAT = (nEdges + 255) / 256;
    const int NB_SCAN = (nNodes + 255) / 256;

    // ---- one-time: CSR build + weight prep ----
    hipMemsetAsync(deg, 0, (size_t)nNodes * sizeof(int), stream);
    hipMemsetAsync(colsum, 0, 64 * sizeof(float), stream);
    hipMemsetAsync(agg, 0, (size_t)nNodes * 64 * sizeof(float), stream);
    k_hist<<<NB_FLAT, 256, 0, stream>>>(dst, deg, nEdges);
    k_scan1<<<NB_SCAN, 256, 0, stream>>>(deg, local, bsum, nNodes);
    k_scan2<<<1, 256, 0, stream>>>(bsum, NB_SCAN);
    k_scan3<<<NB_SCAN, 256, 0, stream>>>(local, bsum, cursor, nNodes);
    k_scatter<<<NB_FLAT, 256, 0, stream>>>(src, dst, ea, cursor, rec, nEdges);
    k_wprep<<<(WP_TOTAL + 255) / 256, 256, 0, stream>>>(lin_w, mw1, mw2, uw1, uw2, wpH, wpL);

    k_in<<<NB_T, 256, 0, stream>>>(x, wpH + OFF_IN, wpL + OFF_IN, lin_b, h, nNodes);

    for (int l = 0; l < 4; ++l) {
        k_pre<<<NB_T, 256, 0, stream>>>(h, wpH + OFF_PRE(l), wpL + OFF_PRE(l),
            mb1 + l * 64, Pb, Qb, nNodes);
        k_edge<<<NB_EDGE, 256, 0, stream>>>(Pb, Qb, rec,
            mw1 + (size_t)l * 134 * 64 + 128 * 64,
            wpH + OFF_MW2(l), wpL + OFF_MW2(l), mb2 + l * 64, agg, nEdges);
        k_upd1<<<NB_T, 256, 0, stream>>>(h, agg,
            wpH + OFF_UW1(l), wpL + OFF_UW1(l), ub1 + l * 64, agg, nNodes);
        k_upd2<<<NB_T, 256, 0, stream>>>(h, agg,
            wpH + OFF_UW2(l), wpL + OFF_UW2(l), ub2 + l * 64,
            colsum, nNodes, (l == 3) ? 1 : 0);
    }

    k_out<<<1, 64, 0, stream>>>(colsum, pw, pb, (float*)d_out, nNodes);
}

// Round 16
// 538.030 us; speedup vs baseline: 1.1122x; 1.1122x over previous
//
#include <hip/hip_runtime.h>
#include <hip/hip_fp16.h>

// MPNN on MI355X.
//
// Algebra: msg layer-1 is linear before its relu:
//   m1 = relu(P[dst] + Q[src] + ea@W1e + b1), P = h@W1[0:64]+b1, Q = h@W1[64:128]
// R3: m2 GEMM via MFMA. R4: dst-sorted CSR, consumer-side aggregation.
// R5-R7: flat 32-edge batches, readlane metadata, ballot segment mask,
//     per-segment coalesced atomic. R12: fragment-layout weights.
// R17 (WIN, 642us): k_edge weight B-frags -> block-shared LDS. 87->67us.
// R26-R28 (WIN, 561.8us): fp16x2 packed m1 (P/Q/m1/W2 fp16, v_pk ops,
//     f16 MFMA); readlane-pair + cndmask row select (no bpermute).
// R29 (WIN, 552.2us): k_scatter 32B packed records killed 5x write amp.
// R30 (REGRESSION, 598us): NB_T 392->784 single-var test: k_upd2 51->86us
//     with occ DOUBLED and BW halved. "1-tile/wave loses" is REAL: node
//     kernels pay a big per-wave prologue; halving tiles/wave doubles it.
//     Also re-attributes R18: its k_upd2 explosion (88us) was the GRID,
//     not LDS weights. NB_T=392 restored.
// R31: fuse k_upd1+k_upd2 into k_upd. tv round-trip (12.8MB write + read
//     + zero + one full latency pass) eliminated: per tile, stage [h|agg]
//     -> U1 MFMA (regs, k_upd1 shape) -> relu -> bf16 tile in LDS ->
//     U2 MFMA (LDS-staged weights, k_edge pattern) -> relu -> RMW h +
//     colsum. agg zeroed after stage-load drain (wave owns rows).
//     Numerics identical (f2bf applied to same value, f32 trip skipped).
//     Pair traffic 102->64MB, one latency pass gone.

typedef __attribute__((ext_vector_type(8))) short short8;
typedef __attribute__((ext_vector_type(4))) float float4v;

__device__ __forceinline__ unsigned short f2bf(float f) {
    unsigned int u = __float_as_uint(f);
    unsigned int r = u + 0x7fff + ((u >> 16) & 1);   // RTNE
    return (unsigned short)(r >> 16);
}
__device__ __forceinline__ float bf2f(unsigned short u) {
    return __uint_as_float(((unsigned int)u) << 16);
}
__device__ __forceinline__ __half2 u2h2(unsigned int u) {
    union { unsigned int u; __half2 h; } c; c.u = u; return c.h;
}
__device__ __forceinline__ unsigned int h22u(__half2 h) {
    union { unsigned int u; __half2 h; } c; c.h = h; return c.u;
}
// ROCm 7.2 lacks __hmax2; gfx950 has v_pk_max_f16 — emit it directly.
__device__ __forceinline__ unsigned int pkmax0(unsigned int a) {
    unsigned int r;
    asm("v_pk_max_f16 %0, %1, %2" : "=v"(r) : "v"(a), "v"(0u));
    return r;
}

#define MFMA16(a, b, c)  __builtin_amdgcn_mfma_f32_16x16x32_bf16(a, b, c, 0, 0, 0)
#define MFMA16H(a, b, c) __builtin_amdgcn_mfma_f32_16x16x32_f16(a, b, c, 0, 0, 0)

struct bfpair { short hi, lo; };
__device__ __forceinline__ bfpair wsplit(float wv) {
    bfpair p;
    unsigned short h = f2bf(wv);
    float hf = __uint_as_float(((unsigned int)h) << 16);
    p.hi = (short)h;
    p.lo = (short)f2bf(wv - hf);
    return p;
}

// fragment-layout weight prep offsets (ushort elements)
#define WP_TOTAL 106496
#define OFF_IN   0
#define OFF_PRE(l)  (8192  + (l) * 8192)
#define OFF_MW2(l)  (40960 + (l) * 4096)
#define OFF_UW1(l)  (57344 + (l) * 8192)
#define OFF_UW2(l)  (90112 + (l) * 4096)

// ---------------- weight prep: fp32 -> hi/lo bf16 (fp16 for MW2) ----------------
__global__ __launch_bounds__(256) void k_wprep(const float* __restrict__ lin_w,
        const float* __restrict__ mw1, const float* __restrict__ mw2,
        const float* __restrict__ uw1, const float* __restrict__ uw2,
        unsigned short* __restrict__ H, unsigned short* __restrict__ L) {
    const int tid = blockIdx.x * 256 + threadIdx.x;
    if (tid >= WP_TOTAL) return;
    float val;
    if (tid < 8192) {                                  // lin_in_w: KF=4, NT=4
        int rem = tid;
        int nt = rem >> 11, kf = (rem >> 9) & 3;
        int lane = (rem >> 3) & 63, j = rem & 7;
        int k = kf * 32 + (lane >> 4) * 8 + j;
        val = lin_w[k * 64 + nt * 16 + (lane & 15)];
    } else if (tid < 40960) {                          // msg_w1[0:128]: KF=2, NT=8
        int t = tid - 8192, layer = t >> 13, rem = t & 8191;
        int nt = rem >> 10, kf = (rem >> 9) & 1;
        int lane = (rem >> 3) & 63, j = rem & 7;
        int k = kf * 32 + (lane >> 4) * 8 + j;
        const float* w1 = mw1 + (size_t)layer * 134 * 64;
        val = (nt < 4) ? w1[k * 64 + nt * 16 + (lane & 15)]
                       : w1[(64 + k) * 64 + (nt - 4) * 16 + (lane & 15)];
    } else if (tid < 57344) {                          // msg_w2: KF=2, NT=4 (fp16!)
        int t = tid - 40960, layer = t >> 12, rem = t & 4095;
        int nt = rem >> 10, kf = (rem >> 9) & 1;
        int lane = (rem >> 3) & 63, j = rem & 7;
        int k = kf * 32 + (lane >> 4) * 8 + j;
        val = mw2[(size_t)layer * 4096 + k * 64 + nt * 16 + (lane & 15)];
    } else if (tid < 90112) {                          // upd_w1: KF=4, NT=4
        int t = tid - 57344, layer = t >> 13, rem = t & 8191;
        int nt = rem >> 11, kf = (rem >> 9) & 3;
        int lane = (rem >> 3) & 63, j = rem & 7;
        int k = kf * 32 + (lane >> 4) * 8 + j;
        val = uw1[(size_t)layer * 8192 + k * 64 + nt * 16 + (lane & 15)];
    } else {                                           // upd_w2: KF=2, NT=4
        int t = tid - 90112, layer = t >> 12, rem = t & 4095;
        int nt = rem >> 10, kf = (rem >> 9) & 1;
        int lane = (rem >> 3) & 63, j = rem & 7;
        int k = kf * 32 + (lane >> 4) * 8 + j;
        val = uw2[(size_t)layer * 4096 + k * 64 + nt * 16 + (lane & 15)];
    }
    if (tid >= 40960 && tid < 57344) {                 // fp16 hi/lo for k_edge m2
        __half hh = __float2half_rn(val);
        float hf = __half2float(hh);
        __half hl = __float2half_rn(val - hf);
        H[tid] = __half_as_ushort(hh);
        L[tid] = __half_as_ushort(hl);
    } else {
        bfpair p = wsplit(val);
        H[tid] = (unsigned short)p.hi;
        L[tid] = (unsigned short)p.lo;
    }
}

#define LOADFRAG(dst, arr, nt, KF, kf) \
    dst = *(const short8*)&arr[((((nt) * (KF)) + (kf)) * 64 + lane) * 8]

// ---------------- CSR build (dst bins) ----------------
__global__ __launch_bounds__(256) void k_hist(const int* __restrict__ dst,
        int* __restrict__ deg, int nEdges) {
    int e = blockIdx.x * blockDim.x + threadIdx.x;
    if (e < nEdges) atomicAdd(&deg[dst[e]], 1);
}

__global__ __launch_bounds__(256) void k_scan1(const int* __restrict__ deg,
        int* __restrict__ local, int* __restrict__ bsum, int nNodes) {
    __shared__ int sm[256];
    const int t = threadIdx.x;
    const int n = blockIdx.x * 256 + t;
    int v = (n < nNodes) ? deg[n] : 0;
    sm[t] = v;
    __syncthreads();
    for (int off = 1; off < 256; off <<= 1) {
        int u = (t >= off) ? sm[t - off] : 0;
        __syncthreads();
        sm[t] += u;
        __syncthreads();
    }
    if (n < nNodes) local[n] = sm[t] - v;
    if (t == 255) bsum[blockIdx.x] = sm[255];
}

__global__ __launch_bounds__(256) void k_scan2(int* __restrict__ bsum, int nB) {
    __shared__ int sm[256];
    const int t = threadIdx.x;
    int v = (t < nB) ? bsum[t] : 0;
    sm[t] = v;
    __syncthreads();
    for (int off = 1; off < 256; off <<= 1) {
        int u = (t >= off) ? sm[t - off] : 0;
        __syncthreads();
        sm[t] += u;
        __syncthreads();
    }
    if (t < nB) bsum[t] = sm[t] - v;
}

__global__ __launch_bounds__(256) void k_scan3(const int* __restrict__ local,
        const int* __restrict__ bsum, int* __restrict__ cursor, int nNodes) {
    int n = blockIdx.x * 256 + threadIdx.x;
    if (n < nNodes) cursor[n] = bsum[blockIdx.x] + local[n];
}

// R29: one 32B packed record per edge: {src, dst, ea[0..5]}, 2x float4.
__global__ __launch_bounds__(256) void k_scatter(const int* __restrict__ src,
        const int* __restrict__ dst, const float* __restrict__ ea,
        int* __restrict__ cursor, float* __restrict__ rec, int nEdges) {
    int e = blockIdx.x * blockDim.x + threadIdx.x;
    if (e < nEdges) {
        int d = dst[e];
        int s = src[e];
        int pos = atomicAdd(&cursor[d], 1);
        const float* p = ea + (size_t)e * 6;
        float4 lo, hi;
        lo.x = __int_as_float(s);
        lo.y = __int_as_float(d);
        lo.z = p[0];
        lo.w = p[1];
        hi.x = p[2];
        hi.y = p[3];
        hi.z = p[4];
        hi.w = p[5];
        float4* q = (float4*)(rec + (size_t)pos * 8);
        q[0] = lo;
        q[1] = hi;
    }
}

// ---------------- node-side MFMA GEMM kernels ----------------
// A-frag: A[m=col][k=quad*8+j]; C: col=lane&15, row=quad*4+reg (verified).

// h = x @ Win + b   (K=128, N=64)
__global__ __launch_bounds__(256) void k_in(const float* __restrict__ x,
        const unsigned short* __restrict__ wh, const unsigned short* __restrict__ wl,
        const float* __restrict__ bia, float* __restrict__ h, int nNodes) {
    const int lane = threadIdx.x & 63;
    const int wib  = threadIdx.x >> 6;
    const int quad = lane >> 4, col = lane & 15;
    __shared__ unsigned short sm[4][16 * 136];
    unsigned short* __restrict__ mt = sm[wib];

    short8 bh[4][4], bl[4][4];
#pragma unroll
    for (int nt = 0; nt < 4; ++nt)
#pragma unroll
        for (int kf = 0; kf < 4; ++kf) {
            LOADFRAG(bh[nt][kf], wh, nt, 4, kf);
            LOADFRAG(bl[nt][kf], wl, nt, 4, kf);
        }
    float bv[4];
#pragma unroll
    for (int nt = 0; nt < 4; ++nt) bv[nt] = bia[nt * 16 + col];

    const int nTiles = (nNodes + 15) >> 4;
    const int wid = blockIdx.x * 4 + wib;
    const int nw  = gridDim.x * 4;
    for (int tile = wid; tile < nTiles; tile += nw) {
        const int base = tile * 16;
#pragma unroll
        for (int j = 0; j < 16; ++j) {
            int row = min(base + j, nNodes - 1);
            mt[j * 136 + lane]      = f2bf(x[(size_t)row * 128 + lane]);
            mt[j * 136 + 64 + lane] = f2bf(x[(size_t)row * 128 + 64 + lane]);
        }
        __builtin_amdgcn_s_waitcnt(0);
        short8 a[4];
#pragma unroll
        for (int kf = 0; kf < 4; ++kf)
            a[kf] = *(const short8*)&mt[col * 136 + kf * 32 + quad * 8];
#pragma unroll
        for (int nt = 0; nt < 4; ++nt) {
            float4v c = {0.f, 0.f, 0.f, 0.f};
#pragma unroll
            for (int kf = 0; kf < 4; ++kf) c = MFMA16(a[kf], bh[nt][kf], c);
#pragma unroll
            for (int kf = 0; kf < 4; ++kf) c = MFMA16(a[kf], bl[nt][kf], c);
#pragma unroll
            for (int r = 0; r < 4; ++r) {
                int row = base + quad * 4 + r;
                if (row < nNodes)
                    h[(size_t)row * 64 + nt * 16 + col] = c[r] + bv[nt];
            }
        }
    }
}

// [P|Q] = h @ [W1[0:64] | W1[64:128]]; P += b1   (K=64, N=128), FP16 outputs
__global__ __launch_bounds__(256) void k_pre(const float* __restrict__ h,
        const unsigned short* __restrict__ wh, const unsigned short* __restrict__ wl,
        const float* __restrict__ b1m,
        unsigned short* __restrict__ P, unsigned short* __restrict__ Q,
        int nNodes) {
    const int lane = threadIdx.x & 63;
    const int wib  = threadIdx.x >> 6;
    const int quad = lane >> 4, col = lane & 15;
    __shared__ unsigned short sm[4][16 * 72];
    unsigned short* __restrict__ mt = sm[wib];

    short8 bh[8][2], bl[8][2];
#pragma unroll
    for (int nt = 0; nt < 8; ++nt)
#pragma unroll
        for (int kf = 0; kf < 2; ++kf) {
            LOADFRAG(bh[nt][kf], wh, nt, 2, kf);
            LOADFRAG(bl[nt][kf], wl, nt, 2, kf);
        }
    float bv1[4];
#pragma unroll
    for (int nt = 0; nt < 4; ++nt) bv1[nt] = b1m[nt * 16 + col];

    const int nTiles = (nNodes + 15) >> 4;
    const int wid = blockIdx.x * 4 + wib;
    const int nw  = gridDim.x * 4;
    for (int tile = wid; tile < nTiles; tile += nw) {
        const int base = tile * 16;
#pragma unroll
        for (int j = 0; j < 16; ++j) {
            int row = min(base + j, nNodes - 1);
            mt[j * 72 + lane] = f2bf(h[(size_t)row * 64 + lane]);
        }
        __builtin_amdgcn_s_waitcnt(0);
        short8 a0 = *(const short8*)&mt[col * 72 + quad * 8];
        short8 a1 = *(const short8*)&mt[col * 72 + 32 + quad * 8];
#pragma unroll
        for (int nt = 0; nt < 8; ++nt) {
            float4v c = {0.f, 0.f, 0.f, 0.f};
            c = MFMA16(a0, bh[nt][0], c);
            c = MFMA16(a1, bh[nt][1], c);
            c = MFMA16(a0, bl[nt][0], c);
            c = MFMA16(a1, bl[nt][1], c);
            unsigned short* __restrict__ outp = (nt < 4) ? P : Q;
            const int nc = (nt & 3) * 16 + col;
            const float badd = (nt < 4) ? bv1[nt & 3] : 0.f;
#pragma unroll
            for (int r = 0; r < 4; ++r) {
                int row = base + quad * 4 + r;
                if (row < nNodes)
                    outp[(size_t)row * 64 + nc] =
                        __half_as_ushort(__float2half_rn(c[r] + badd));
            }
        }
    }
}

// R31 fused update: tv = relu([h|agg]@U1+b1); h += relu(tv@U2+b2);
// zero agg for next layer; optional colsum. U1 in regs, U2 in block LDS.
__global__ __launch_bounds__(256) void k_upd(float* __restrict__ h,
        float* __restrict__ agg,
        const unsigned short* __restrict__ wh1, const unsigned short* __restrict__ wl1,
        const float* __restrict__ b1,
        const unsigned short* __restrict__ wh2, const unsigned short* __restrict__ wl2,
        const float* __restrict__ b2, float* __restrict__ colsum,
        int nNodes, int doCS) {
    const int lane = threadIdx.x & 63;
    const int wib  = threadIdx.x >> 6;
    const int quad = lane >> 4, col = lane & 15;
    __shared__ unsigned short sm[4][16 * 136];   // [h|agg] stage, 17408 B
    __shared__ unsigned short tb[4][16 * 72];    // tv tile (bf16), 9216 B
    __shared__ unsigned short wB[8192];          // U2 [hi|lo] frags, 16384 B
    unsigned short* __restrict__ mt = sm[wib];
    unsigned short* __restrict__ tv = tb[wib];

    // block-cooperative U2 stage
    {
        const short8* __restrict__ sH = (const short8*)wh2;
        const short8* __restrict__ sL = (const short8*)wl2;
        short8* __restrict__ dB = (short8*)wB;
        for (int i = threadIdx.x; i < 512; i += 256) {
            dB[i]       = sH[i];
            dB[512 + i] = sL[i];
        }
    }
    __syncthreads();

    short8 bh[4][4], bl[4][4];                   // U1, registers
#pragma unroll
    for (int nt = 0; nt < 4; ++nt)
#pragma unroll
        for (int kf = 0; kf < 4; ++kf) {
            LOADFRAG(bh[nt][kf], wh1, nt, 4, kf);
            LOADFRAG(bl[nt][kf], wl1, nt, 4, kf);
        }
    float bv1[4], bv2[4];
#pragma unroll
    for (int nt = 0; nt < 4; ++nt) {
        bv1[nt] = b1[nt * 16 + col];
        bv2[nt] = b2[nt * 16 + col];
    }

    float cs0 = 0.f, cs1 = 0.f, cs2 = 0.f, cs3 = 0.f;
    const int nTiles = (nNodes + 15) >> 4;
    const int wid = blockIdx.x * 4 + wib;
    const int nw  = gridDim.x * 4;
    for (int tile = wid; tile < nTiles; tile += nw) {
        const int base = tile * 16;
        // stage [h|agg] -> bf16 LDS
#pragma unroll
        for (int j = 0; j < 16; ++j) {
            int row = min(base + j, nNodes - 1);
            mt[j * 136 + lane]      = f2bf(h[(size_t)row * 64 + lane]);
            mt[j * 136 + 64 + lane] = f2bf(agg[(size_t)row * 64 + lane]);
        }
        __builtin_amdgcn_s_waitcnt(0);   // drains vmcnt too -> safe to zero agg
#pragma unroll
        for (int j = 0; j < 16; ++j) {
            int row = base + j;
            if (row < nNodes) agg[(size_t)row * 64 + lane] = 0.f;
        }
        short8 a[4];
#pragma unroll
        for (int kf = 0; kf < 4; ++kf)
            a[kf] = *(const short8*)&mt[col * 136 + kf * 32 + quad * 8];
        // stage 1: U1 MFMA -> relu -> bf16 tv tile in LDS
#pragma unroll
        for (int nt = 0; nt < 4; ++nt) {
            float4v c = {0.f, 0.f, 0.f, 0.f};
#pragma unroll
            for (int kf = 0; kf < 4; ++kf) c = MFMA16(a[kf], bh[nt][kf], c);
#pragma unroll
            for (int kf = 0; kf < 4; ++kf) c = MFMA16(a[kf], bl[nt][kf], c);
#pragma unroll
            for (int r = 0; r < 4; ++r)
                tv[(quad * 4 + r) * 72 + nt * 16 + col] =
                    f2bf(fmaxf(c[r] + bv1[nt], 0.f));
        }
        __builtin_amdgcn_s_waitcnt(0);   // wave-local LDS drain
        short8 a0 = *(const short8*)&tv[col * 72 + quad * 8];
        short8 a1 = *(const short8*)&tv[col * 72 + 32 + quad * 8];
        // stage 2: U2 MFMA (weights from block LDS) -> relu -> RMW h
#pragma unroll
        for (int nt = 0; nt < 4; ++nt) {
            const short8 h0 = *(const short8*)&wB[((nt * 2 + 0) * 64 + lane) * 8];
            const short8 h1 = *(const short8*)&wB[((nt * 2 + 1) * 64 + lane) * 8];
            const short8 l0 = *(const short8*)&wB[4096 + ((nt * 2 + 0) * 64 + lane) * 8];
            const short8 l1 = *(const short8*)&wB[4096 + ((nt * 2 + 1) * 64 + lane) * 8];
            float4v c = {0.f, 0.f, 0.f, 0.f};
            c = MFMA16(a0, h0, c);
            c = MFMA16(a1, h1, c);
            c = MFMA16(a0, l0, c);
            c = MFMA16(a1, l1, c);
#pragma unroll
            for (int r = 0; r < 4; ++r) {
                int row = base + quad * 4 + r;
                if (row < nNodes) {
                    float* hp = &h[(size_t)row * 64 + nt * 16 + col];
                    float hn = *hp + fmaxf(c[r] + bv2[nt], 0.f);
                    *hp = hn;
                    cs0 += (nt == 0) ? hn : 0.f;
                    cs1 += (nt == 1) ? hn : 0.f;
                    cs2 += (nt == 2) ? hn : 0.f;
                    cs3 += (nt == 3) ? hn : 0.f;
                }
            }
        }
    }
    if (doCS) {
        cs0 += __shfl_xor(cs0, 16); cs0 += __shfl_xor(cs0, 32);
        cs1 += __shfl_xor(cs1, 16); cs1 += __shfl_xor(cs1, 32);
        cs2 += __shfl_xor(cs2, 16); cs2 += __shfl_xor(cs2, 32);
        cs3 += __shfl_xor(cs3, 16); cs3 += __shfl_xor(cs3, 32);
        const float tot = (quad == 0) ? cs0 : (quad == 1) ? cs1
                        : (quad == 2) ? cs2 : cs3;
        atomicAdd(&colsum[lane], tot);   // lane == quad*16+col
    }
}

// ---------------- edge kernel: fp16x2 packed m1, 32-edge batches ----------------
// R17: W2 hi/lo B-frags in block-shared LDS (fp16): hi ushort 0, lo 4096.
// R26-R28: m1 loop = 16 iters x 2 rows (half-wave/row) with v_pk_f16 ops;
//      row metadata via readlane-pair + cndmask (NO bpermute).
// R29: edge data from 32B packed records; ea table = 4 coalesced dword
//      loads of the record block (256 entries; int slots never read).
#define EST 72   // fp16 elems per staged m1 row (144B stride, bank-spread)

__global__ __launch_bounds__(256, 4) void k_edge(const unsigned short* __restrict__ P,
        const unsigned short* __restrict__ Q, const float* __restrict__ rec,
        const float* __restrict__ w1e,
        const unsigned short* __restrict__ wh, const unsigned short* __restrict__ wl,
        const float* __restrict__ b2,
        float* __restrict__ agg, int nEdges) {
    const int lane = threadIdx.x & 63;
    const int wib  = threadIdx.x >> 6;
    const int wid  = blockIdx.x * 4 + wib;
    const int nw   = gridDim.x * 4;
    const int quad = lane >> 4;
    const int col  = lane & 15;
    const int li   = lane & 31;
    const int hs   = lane >> 5;          // half-wave select (0/1)

    __shared__ unsigned short m1b[4][32 * EST];   // 18432 B (fp16 m1)
    __shared__ unsigned int   eab[4][256];        //  4096 B (half2-bcast rec block)
    __shared__ unsigned short wB[8192];           // 16384 B: [hi | lo] fp16 frags
    unsigned short* __restrict__ mt  = m1b[wib];
    unsigned int*   __restrict__ eaw = eab[wib];

    // block-cooperative weight stage: 8 frags hi + 8 frags lo = 1024 short8
    {
        const short8* __restrict__ sH = (const short8*)wh;
        const short8* __restrict__ sL = (const short8*)wl;
        short8* __restrict__ dB = (short8*)wB;
        for (int i = threadIdx.x; i < 512; i += 256) {
            dB[i]       = sH[i];
            dB[512 + i] = sL[i];
        }
    }
    __syncthreads();

    // W1e column-pair weights as half2 (cols 2li, 2li+1)
    __half2 w1ec2[6];
#pragma unroll
    for (int jj = 0; jj < 6; ++jj)
        w1ec2[jj] = __halves2half2(__float2half_rn(w1e[jj * 64 + 2 * li]),
                                   __float2half_rn(w1e[jj * 64 + 2 * li + 1]));

    float b2v[4];
#pragma unroll
    for (int nt = 0; nt < 4; ++nt) b2v[nt] = b2[nt * 16 + col];

    // contiguous chunk per wave: dst-sorted records -> P/agg locality
    const int nBatch = (nEdges + 31) >> 5;
    const int per = nBatch / nw, rem = nBatch % nw;
    const int btLo = wid * per + min(wid, rem);
    const int btHi = btLo + per + (wid < rem ? 1 : 0);

    const int* __restrict__ reci = (const int*)rec;

    for (int bt = btLo; bt < btHi; ++bt) {
        const int base = __builtin_amdgcn_readfirstlane(bt << 5);
        const int gidx = min(base + li, nEdges - 1);
        const int vsj = reci[(size_t)gidx * 8];       // row li's src
        const int vdj = reci[(size_t)gidx * 8 + 1];   // row li's dst (lanes 32-63 dup)
        const int vprev = __shfl_up(vdj, 1);
        unsigned long long bmask =
            __ballot(lane < 32 && (li == 0 || vdj != vprev));
        bmask |= (1ull << 32) | 1ull;

        // ---- record block -> half2-broadcast LDS table (4 coalesced loads) ----
        const int fMax = nEdges * 8 - 1;
        const int fBase = base * 8;
#pragma unroll
        for (int k = 0; k < 4; ++k)
            eaw[k * 64 + lane] =
                h22u(__float2half2_rn(rec[min(fBase + k * 64 + lane, fMax)]));

        // ---- m1: 16 iters x 2 rows, fp16x2 column pairs ----
        // row select via readlane-pair (compile-time lanes) + cndmask.
#pragma unroll
        for (int j = 0; j < 16; ++j) {
            const int d0 = __builtin_amdgcn_readlane(vdj, 2 * j);
            const int d1 = __builtin_amdgcn_readlane(vdj, 2 * j + 1);
            const int s0 = __builtin_amdgcn_readlane(vsj, 2 * j);
            const int s1 = __builtin_amdgcn_readlane(vsj, 2 * j + 1);
            const int d = hs ? d1 : d0;
            const int s = hs ? s1 : s0;
            const int rsel = 2 * j + hs;               // this half-wave's row
            const unsigned int p2 = *(const unsigned int*)&P[(size_t)d * 64 + 2 * li];
            const unsigned int q2 = *(const unsigned int*)&Q[(size_t)s * 64 + 2 * li];
            __half2 t = __hadd2(u2h2(p2), u2h2(q2));
#pragma unroll
            for (int jj = 0; jj < 6; ++jj) {
                // record rsel, float slot 2+jj -> table index rsel*8 + 2 + jj
                const unsigned int eu = eaw[16 * j + 8 * hs + 2 + jj];
                t = __hfma2(u2h2(eu), w1ec2[jj], t);
            }
            *(unsigned int*)((char*)mt + rsel * (EST * 2) + li * 4) = pkmax0(h22u(t));
        }
        __builtin_amdgcn_s_waitcnt(0);   // wave-local LDS drain

        short8 a00 = *(const short8*)&mt[col * EST + quad * 8];
        short8 a01 = *(const short8*)&mt[col * EST + 32 + quad * 8];
        short8 a10 = *(const short8*)&mt[(16 + col) * EST + quad * 8];
        short8 a11 = *(const short8*)&mt[(16 + col) * EST + 32 + quad * 8];

        // m2 (fp16 MFMA, same frag layout) for both 16-row tiles
        float4v m2v[2][4];
#pragma unroll
        for (int nt = 0; nt < 4; ++nt) {
            const short8 h0 = *(const short8*)&wB[((nt * 2 + 0) * 64 + lane) * 8];
            const short8 h1 = *(const short8*)&wB[((nt * 2 + 1) * 64 + lane) * 8];
            const short8 l0 = *(const short8*)&wB[4096 + ((nt * 2 + 0) * 64 + lane) * 8];
            const short8 l1 = *(const short8*)&wB[4096 + ((nt * 2 + 1) * 64 + lane) * 8];
            float4v c0 = {0.f, 0.f, 0.f, 0.f};
            float4v c1 = {0.f, 0.f, 0.f, 0.f};
            c0 = MFMA16H(a00, h0, c0);
            c0 = MFMA16H(a01, h1, c0);
            c0 = MFMA16H(a00, l0, c0);
            c0 = MFMA16H(a01, l1, c0);
            c1 = MFMA16H(a10, h0, c1);
            c1 = MFMA16H(a11, h1, c1);
            c1 = MFMA16H(a10, l0, c1);
            c1 = MFMA16H(a11, l1, c1);
#pragma unroll
            for (int r = 0; r < 4; ++r) {
                const bool v0 = base + (quad * 4 + r) < nEdges;
                const bool v1 = base + 16 + (quad * 4 + r) < nEdges;
                m2v[0][nt][r] = v0 ? fmaxf(c0[r] + b2v[nt], 0.f) : 0.f;
                m2v[1][nt][r] = v1 ? fmaxf(c1[r] + b2v[nt], 0.f) : 0.f;
            }
        }

        // ---- segmented reduce + one coalesced atomic per segment ----
        int r0 = 0;
        while (r0 < 32) {
            const int nid = __builtin_amdgcn_readlane(vdj, r0);
            const int r1 = r0 + 1 + (int)__builtin_ctzll(bmask >> (r0 + 1));
            float s0 = 0.f, s1 = 0.f, s2 = 0.f, s3 = 0.f;
#pragma unroll
            for (int t = 0; t < 2; ++t)
#pragma unroll
                for (int r = 0; r < 4; ++r) {
                    const int R = t * 16 + quad * 4 + r;
                    const bool in = (R >= r0) && (R < r1);
                    s0 += in ? m2v[t][0][r] : 0.f;
                    s1 += in ? m2v[t][1][r] : 0.f;
                    s2 += in ? m2v[t][2][r] : 0.f;
                    s3 += in ? m2v[t][3][r] : 0.f;
                }
            s0 += __shfl_xor(s0, 16); s0 += __shfl_xor(s0, 32);
            s1 += __shfl_xor(s1, 16); s1 += __shfl_xor(s1, 32);
            s2 += __shfl_xor(s2, 16); s2 += __shfl_xor(s2, 32);
            s3 += __shfl_xor(s3, 16); s3 += __shfl_xor(s3, 32);
            const float tot = (quad == 0) ? s0 : (quad == 1) ? s1
                            : (quad == 2) ? s2 : s3;
            atomicAdd(&agg[(size_t)nid * 64 + lane], tot);
            r0 = r1;
        }
    }
}

__global__ void k_out(const float* __restrict__ colsum, const float* __restrict__ pw,
                      const float* __restrict__ pb, float* __restrict__ out, int nNodes) {
    const int lane = threadIdx.x;
    float v = colsum[lane] * pw[lane];
#pragma unroll
    for (int off = 32; off; off >>= 1) v += __shfl_down(v, off);
    if (lane == 0) out[0] = v + (float)nNodes * pb[0];
}

extern "C" void kernel_launch(void* const* d_in, const int* in_sizes, int n_in,
                              void* d_out, int out_size, void* d_ws, size_t ws_size,
                              hipStream_t stream) {
    const float* x     = (const float*)d_in[0];
    const int*   ei    = (const int*)d_in[1];
    const float* ea    = (const float*)d_in[2];
    const float* lin_w = (const float*)d_in[3];
    const float* lin_b = (const float*)d_in[4];
    const float* mw1   = (const float*)d_in[5];
    const float* mb1   = (const float*)d_in[6];
    const float* mw2   = (const float*)d_in[7];
    const float* mb2   = (const float*)d_in[8];
    const float* uw1   = (const float*)d_in[9];
    const float* ub1   = (const float*)d_in[10];
    const float* uw2   = (const float*)d_in[11];
    const float* ub2   = (const float*)d_in[12];
    const float* pw    = (const float*)d_in[13];
    const float* pb    = (const float*)d_in[14];

    const int nNodes = in_sizes[0] / 128;
    const int nEdges = in_sizes[1] / 2;
    const int* src = ei;            // edge_index[0]
    const int* dst = ei + nEdges;   // edge_index[1]

    // workspace layout (floats, then ushorts, then ints)
    float* h       = (float*)d_ws;
    float* agg     = h   + (size_t)nNodes * 64;
    float* rec     = agg + (size_t)nNodes * 64;   // 32B packed edge records
    float* colsum  = rec + (size_t)nEdges * 8;
    unsigned short* Pb  = (unsigned short*)(colsum + 64);
    unsigned short* Qb  = Pb + (size_t)nNodes * 64;
    unsigned short* wpH = Qb + (size_t)nNodes * 64;
    unsigned short* wpL = wpH + WP_TOTAL;
    int*   deg     = (int*)(wpL + WP_TOTAL);
    int*   cursor  = deg + nNodes;
    int*   local   = cursor + nNodes;
    int*   bsum    = local + nNodes;

    const int NB_T    = 392;                     // node-GEMM tiles: ~2/wave (measured sweet spot)
    const int NB_EDGE = 2048;
    const int NB_FLAT = (nEdges + 255) / 256;
    const int NB_SCAN = (nNodes + 255) / 256;

    // ---- one-time: CSR build + weight prep ----
    hipMemsetAsync(deg, 0, (size_t)nNodes * sizeof(int), stream);
    hipMemsetAsync(colsum, 0, 64 * sizeof(float), stream);
    hipMemsetAsync(agg, 0, (size_t)nNodes * 64 * sizeof(float), stream);
    k_hist<<<NB_FLAT, 256, 0, stream>>>(dst, deg, nEdges);
    k_scan1<<<NB_SCAN, 256, 0, stream>>>(deg, local, bsum, nNodes);
    k_scan2<<<1, 256, 0, stream>>>(bsum, NB_SCAN);
    k_scan3<<<NB_SCAN, 256, 0, stream>>>(local, bsum, cursor, nNodes);
    k_scatter<<<NB_FLAT, 256, 0, stream>>>(src, dst, ea, cursor, rec, nEdges);
    k_wprep<<<(WP_TOTAL + 255) / 256, 256, 0, stream>>>(lin_w, mw1, mw2, uw1, uw2, wpH, wpL);

    k_in<<<NB_T, 256, 0, stream>>>(x, wpH + OFF_IN, wpL + OFF_IN, lin_b, h, nNodes);

    for (int l = 0; l < 4; ++l) {
        k_pre<<<NB_T, 256, 0, stream>>>(h, wpH + OFF_PRE(l), wpL + OFF_PRE(l),
            mb1 + l * 64, Pb, Qb, nNodes);
        k_edge<<<NB_EDGE, 256, 0, stream>>>(Pb, Qb, rec,
            mw1 + (size_t)l * 134 * 64 + 128 * 64,
            wpH + OFF_MW2(l), wpL + OFF_MW2(l), mb2 + l * 64, agg, nEdges);
        k_upd<<<NB_T, 256, 0, stream>>>(h, agg,
            wpH + OFF_UW1(l), wpL + OFF_UW1(l), ub1 + l * 64,
            wpH + OFF_UW2(l), wpL + OFF_UW2(l), ub2 + l * 64,
            colsum, nNodes, (l == 3) ? 1 : 0);
    }

    k_out<<<1, 64, 0, stream>>>(colsum, pw, pb, (float*)d_out, nNodes);
}

// Round 18
// 526.135 us; speedup vs baseline: 1.1373x; 1.0226x over previous
//
#include <hip/hip_runtime.h>
#include <hip/hip_fp16.h>

// MPNN on MI355X.
//
// Algebra: msg layer-1 is linear before its relu:
//   m1 = relu(P[dst] + Q[src] + ea@W1e + b1), P = h@W1[0:64]+b1, Q = h@W1[64:128]
// R3: m2 GEMM via MFMA. R4: dst-sorted CSR, consumer-side aggregation.
// R5-R7: flat 32-edge batches, readlane metadata, ballot segment mask,
//     per-segment coalesced atomic. R12: fragment-layout weights.
// R17 (WIN, 642us): k_edge weight B-frags -> block-shared LDS. 87->67us.
// R26-R28 (WIN, 561.8us): fp16x2 packed m1; readlane-pair row select.
// R29 (WIN, 552.2us): k_scatter 32B packed records (5x write amp killed).
// R30 (REGRESSION): 1-tile/wave grids lose (prologue doubling). NB_T=392.
// R31 (WIN, 538.0us): k_upd1+k_upd2 fused (tv round-trip + one pass gone).
// R32 (NaN BUG): fused k_pre sized wP for 8 frags but W1 pre-GEMM has
//     NT=8 x KF=2 = 16 frags; stage-3 reads for nt>=4 ran past wP into
//     unrelated LDS -> garbage weights -> NaN.
// R33: R32 with wP fixed: stage W1(l+1) as SINGLE fp16 frags (hi+lo
//     converted during cooperative stage): 16 frags = exactly 8192
//     ushorts = 16KB; LDS 59.4KB fits. Numerics IMPROVE vs standalone
//     k_pre (fp16 weights 2^-12 vs bf16-pair; hn A-operand fp16 2^-11 vs
//     bf16-staged 2^-8; P/Q fp16-quantized at storage anyway). Stage 3 =
//     2x MFMA16H per nt. Layers 1-3 k_pre dispatches + 3 full h passes
//     eliminated.

typedef __attribute__((ext_vector_type(8))) short short8;
typedef __attribute__((ext_vector_type(4))) float float4v;

__device__ __forceinline__ unsigned short f2bf(float f) {
    unsigned int u = __float_as_uint(f);
    unsigned int r = u + 0x7fff + ((u >> 16) & 1);   // RTNE
    return (unsigned short)(r >> 16);
}
__device__ __forceinline__ float bf2f(unsigned short u) {
    return __uint_as_float(((unsigned int)u) << 16);
}
__device__ __forceinline__ __half2 u2h2(unsigned int u) {
    union { unsigned int u; __half2 h; } c; c.u = u; return c.h;
}
__device__ __forceinline__ unsigned int h22u(__half2 h) {
    union { unsigned int u; __half2 h; } c; c.h = h; return c.u;
}
// ROCm 7.2 lacks __hmax2; gfx950 has v_pk_max_f16 — emit it directly.
__device__ __forceinline__ unsigned int pkmax0(unsigned int a) {
    unsigned int r;
    asm("v_pk_max_f16 %0, %1, %2" : "=v"(r) : "v"(a), "v"(0u));
    return r;
}

#define MFMA16(a, b, c)  __builtin_amdgcn_mfma_f32_16x16x32_bf16(a, b, c, 0, 0, 0)
#define MFMA16H(a, b, c) __builtin_amdgcn_mfma_f32_16x16x32_f16(a, b, c, 0, 0, 0)

struct bfpair { short hi, lo; };
__device__ __forceinline__ bfpair wsplit(float wv) {
    bfpair p;
    unsigned short h = f2bf(wv);
    float hf = __uint_as_float(((unsigned int)h) << 16);
    p.hi = (short)h;
    p.lo = (short)f2bf(wv - hf);
    return p;
}

// fragment-layout weight prep offsets (ushort elements)
#define WP_TOTAL 106496
#define OFF_IN   0
#define OFF_PRE(l)  (8192  + (l) * 8192)
#define OFF_MW2(l)  (40960 + (l) * 4096)
#define OFF_UW1(l)  (57344 + (l) * 8192)
#define OFF_UW2(l)  (90112 + (l) * 4096)

// ---------------- weight prep: fp32 -> hi/lo bf16 (fp16 for MW2) ----------------
__global__ __launch_bounds__(256) void k_wprep(const float* __restrict__ lin_w,
        const float* __restrict__ mw1, const float* __restrict__ mw2,
        const float* __restrict__ uw1, const float* __restrict__ uw2,
        unsigned short* __restrict__ H, unsigned short* __restrict__ L) {
    const int tid = blockIdx.x * 256 + threadIdx.x;
    if (tid >= WP_TOTAL) return;
    float val;
    if (tid < 8192) {                                  // lin_in_w: KF=4, NT=4
        int rem = tid;
        int nt = rem >> 11, kf = (rem >> 9) & 3;
        int lane = (rem >> 3) & 63, j = rem & 7;
        int k = kf * 32 + (lane >> 4) * 8 + j;
        val = lin_w[k * 64 + nt * 16 + (lane & 15)];
    } else if (tid < 40960) {                          // msg_w1[0:128]: KF=2, NT=8
        int t = tid - 8192, layer = t >> 13, rem = t & 8191;
        int nt = rem >> 10, kf = (rem >> 9) & 1;
        int lane = (rem >> 3) & 63, j = rem & 7;
        int k = kf * 32 + (lane >> 4) * 8 + j;
        const float* w1 = mw1 + (size_t)layer * 134 * 64;
        val = (nt < 4) ? w1[k * 64 + nt * 16 + (lane & 15)]
                       : w1[(64 + k) * 64 + (nt - 4) * 16 + (lane & 15)];
    } else if (tid < 57344) {                          // msg_w2: KF=2, NT=4 (fp16!)
        int t = tid - 40960, layer = t >> 12, rem = t & 4095;
        int nt = rem >> 10, kf = (rem >> 9) & 1;
        int lane = (rem >> 3) & 63, j = rem & 7;
        int k = kf * 32 + (lane >> 4) * 8 + j;
        val = mw2[(size_t)layer * 4096 + k * 64 + nt * 16 + (lane & 15)];
    } else if (tid < 90112) {                          // upd_w1: KF=4, NT=4
        int t = tid - 57344, layer = t >> 13, rem = t & 8191;
        int nt = rem >> 11, kf = (rem >> 9) & 3;
        int lane = (rem >> 3) & 63, j = rem & 7;
        int k = kf * 32 + (lane >> 4) * 8 + j;
        val = uw1[(size_t)layer * 8192 + k * 64 + nt * 16 + (lane & 15)];
    } else {                                           // upd_w2: KF=2, NT=4
        int t = tid - 90112, layer = t >> 12, rem = t & 4095;
        int nt = rem >> 10, kf = (rem >> 9) & 1;
        int lane = (rem >> 3) & 63, j = rem & 7;
        int k = kf * 32 + (lane >> 4) * 8 + j;
        val = uw2[(size_t)layer * 4096 + k * 64 + nt * 16 + (lane & 15)];
    }
    if (tid >= 40960 && tid < 57344) {                 // fp16 hi/lo for k_edge m2
        __half hh = __float2half_rn(val);
        float hf = __half2float(hh);
        __half hl = __float2half_rn(val - hf);
        H[tid] = __half_as_ushort(hh);
        L[tid] = __half_as_ushort(hl);
    } else {
        bfpair p = wsplit(val);
        H[tid] = (unsigned short)p.hi;
        L[tid] = (unsigned short)p.lo;
    }
}

#define LOADFRAG(dst, arr, nt, KF, kf) \
    dst = *(const short8*)&arr[((((nt) * (KF)) + (kf)) * 64 + lane) * 8]

// ---------------- CSR build (dst bins) ----------------
__global__ __launch_bounds__(256) void k_hist(const int* __restrict__ dst,
        int* __restrict__ deg, int nEdges) {
    int e = blockIdx.x * blockDim.x + threadIdx.x;
    if (e < nEdges) atomicAdd(&deg[dst[e]], 1);
}

__global__ __launch_bounds__(256) void k_scan1(const int* __restrict__ deg,
        int* __restrict__ local, int* __restrict__ bsum, int nNodes) {
    __shared__ int sm[256];
    const int t = threadIdx.x;
    const int n = blockIdx.x * 256 + t;
    int v = (n < nNodes) ? deg[n] : 0;
    sm[t] = v;
    __syncthreads();
    for (int off = 1; off < 256; off <<= 1) {
        int u = (t >= off) ? sm[t - off] : 0;
        __syncthreads();
        sm[t] += u;
        __syncthreads();
    }
    if (n < nNodes) local[n] = sm[t] - v;
    if (t == 255) bsum[blockIdx.x] = sm[255];
}

__global__ __launch_bounds__(256) void k_scan2(int* __restrict__ bsum, int nB) {
    __shared__ int sm[256];
    const int t = threadIdx.x;
    int v = (t < nB) ? bsum[t] : 0;
    sm[t] = v;
    __syncthreads();
    for (int off = 1; off < 256; off <<= 1) {
        int u = (t >= off) ? sm[t - off] : 0;
        __syncthreads();
        sm[t] += u;
        __syncthreads();
    }
    if (t < nB) bsum[t] = sm[t] - v;
}

__global__ __launch_bounds__(256) void k_scan3(const int* __restrict__ local,
        const int* __restrict__ bsum, int* __restrict__ cursor, int nNodes) {
    int n = blockIdx.x * 256 + threadIdx.x;
    if (n < nNodes) cursor[n] = bsum[blockIdx.x] + local[n];
}

// R29: one 32B packed record per edge: {src, dst, ea[0..5]}, 2x float4.
__global__ __launch_bounds__(256) void k_scatter(const int* __restrict__ src,
        const int* __restrict__ dst, const float* __restrict__ ea,
        int* __restrict__ cursor, float* __restrict__ rec, int nEdges) {
    int e = blockIdx.x * blockDim.x + threadIdx.x;
    if (e < nEdges) {
        int d = dst[e];
        int s = src[e];
        int pos = atomicAdd(&cursor[d], 1);
        const float* p = ea + (size_t)e * 6;
        float4 lo, hi;
        lo.x = __int_as_float(s);
        lo.y = __int_as_float(d);
        lo.z = p[0];
        lo.w = p[1];
        hi.x = p[2];
        hi.y = p[3];
        hi.z = p[4];
        hi.w = p[5];
        float4* q = (float4*)(rec + (size_t)pos * 8);
        q[0] = lo;
        q[1] = hi;
    }
}

// ---------------- node-side MFMA GEMM kernels ----------------
// A-frag: A[m=col][k=quad*8+j]; C: col=lane&15, row=quad*4+reg (verified).

// h = x @ Win + b   (K=128, N=64)
__global__ __launch_bounds__(256) void k_in(const float* __restrict__ x,
        const unsigned short* __restrict__ wh, const unsigned short* __restrict__ wl,
        const float* __restrict__ bia, float* __restrict__ h, int nNodes) {
    const int lane = threadIdx.x & 63;
    const int wib  = threadIdx.x >> 6;
    const int quad = lane >> 4, col = lane & 15;
    __shared__ unsigned short sm[4][16 * 136];
    unsigned short* __restrict__ mt = sm[wib];

    short8 bh[4][4], bl[4][4];
#pragma unroll
    for (int nt = 0; nt < 4; ++nt)
#pragma unroll
        for (int kf = 0; kf < 4; ++kf) {
            LOADFRAG(bh[nt][kf], wh, nt, 4, kf);
            LOADFRAG(bl[nt][kf], wl, nt, 4, kf);
        }
    float bv[4];
#pragma unroll
    for (int nt = 0; nt < 4; ++nt) bv[nt] = bia[nt * 16 + col];

    const int nTiles = (nNodes + 15) >> 4;
    const int wid = blockIdx.x * 4 + wib;
    const int nw  = gridDim.x * 4;
    for (int tile = wid; tile < nTiles; tile += nw) {
        const int base = tile * 16;
#pragma unroll
        for (int j = 0; j < 16; ++j) {
            int row = min(base + j, nNodes - 1);
            mt[j * 136 + lane]      = f2bf(x[(size_t)row * 128 + lane]);
            mt[j * 136 + 64 + lane] = f2bf(x[(size_t)row * 128 + 64 + lane]);
        }
        __builtin_amdgcn_s_waitcnt(0);
        short8 a[4];
#pragma unroll
        for (int kf = 0; kf < 4; ++kf)
            a[kf] = *(const short8*)&mt[col * 136 + kf * 32 + quad * 8];
#pragma unroll
        for (int nt = 0; nt < 4; ++nt) {
            float4v c = {0.f, 0.f, 0.f, 0.f};
#pragma unroll
            for (int kf = 0; kf < 4; ++kf) c = MFMA16(a[kf], bh[nt][kf], c);
#pragma unroll
            for (int kf = 0; kf < 4; ++kf) c = MFMA16(a[kf], bl[nt][kf], c);
#pragma unroll
            for (int r = 0; r < 4; ++r) {
                int row = base + quad * 4 + r;
                if (row < nNodes)
                    h[(size_t)row * 64 + nt * 16 + col] = c[r] + bv[nt];
            }
        }
    }
}

// [P|Q] = h @ [W1[0:64] | W1[64:128]]; P += b1   (K=64, N=128), FP16 outputs
// (standalone: used only for layer 0; layers 1-3 fused into k_upd)
__global__ __launch_bounds__(256) void k_pre(const float* __restrict__ h,
        const unsigned short* __restrict__ wh, const unsigned short* __restrict__ wl,
        const float* __restrict__ b1m,
        unsigned short* __restrict__ P, unsigned short* __restrict__ Q,
        int nNodes) {
    const int lane = threadIdx.x & 63;
    const int wib  = threadIdx.x >> 6;
    const int quad = lane >> 4, col = lane & 15;
    __shared__ unsigned short sm[4][16 * 72];
    unsigned short* __restrict__ mt = sm[wib];

    short8 bh[8][2], bl[8][2];
#pragma unroll
    for (int nt = 0; nt < 8; ++nt)
#pragma unroll
        for (int kf = 0; kf < 2; ++kf) {
            LOADFRAG(bh[nt][kf], wh, nt, 2, kf);
            LOADFRAG(bl[nt][kf], wl, nt, 2, kf);
        }
    float bv1[4];
#pragma unroll
    for (int nt = 0; nt < 4; ++nt) bv1[nt] = b1m[nt * 16 + col];

    const int nTiles = (nNodes + 15) >> 4;
    const int wid = blockIdx.x * 4 + wib;
    const int nw  = gridDim.x * 4;
    for (int tile = wid; tile < nTiles; tile += nw) {
        const int base = tile * 16;
#pragma unroll
        for (int j = 0; j < 16; ++j) {
            int row = min(base + j, nNodes - 1);
            mt[j * 72 + lane] = f2bf(h[(size_t)row * 64 + lane]);
        }
        __builtin_amdgcn_s_waitcnt(0);
        short8 a0 = *(const short8*)&mt[col * 72 + quad * 8];
        short8 a1 = *(const short8*)&mt[col * 72 + 32 + quad * 8];
#pragma unroll
        for (int nt = 0; nt < 8; ++nt) {
            float4v c = {0.f, 0.f, 0.f, 0.f};
            c = MFMA16(a0, bh[nt][0], c);
            c = MFMA16(a1, bh[nt][1], c);
            c = MFMA16(a0, bl[nt][0], c);
            c = MFMA16(a1, bl[nt][1], c);
            unsigned short* __restrict__ outp = (nt < 4) ? P : Q;
            const int nc = (nt & 3) * 16 + col;
            const float badd = (nt < 4) ? bv1[nt & 3] : 0.f;
#pragma unroll
            for (int r = 0; r < 4; ++r) {
                int row = base + quad * 4 + r;
                if (row < nNodes)
                    outp[(size_t)row * 64 + nc] =
                        __half_as_ushort(__float2half_rn(c[r] + badd));
            }
        }
    }
}

// R31/R33 fused update: tv = relu([h|agg]@U1+b1); h += relu(tv@U2+b2);
// zero agg; optional colsum; if doPre: P/Q = hn @ W1(l+1) (+b1) fp16.
// U1 in regs, U2 in block LDS (bf16 hi/lo), W1(l+1) in block LDS as
// SINGLE fp16 frags (16 frags = exactly 8192 ushorts; R32's OOB fixed).
__global__ __launch_bounds__(256) void k_upd(float* __restrict__ h,
        float* __restrict__ agg,
        const unsigned short* __restrict__ wh1, const unsigned short* __restrict__ wl1,
        const float* __restrict__ b1,
        const unsigned short* __restrict__ wh2, const unsigned short* __restrict__ wl2,
        const float* __restrict__ b2,
        const unsigned short* __restrict__ whP, const unsigned short* __restrict__ wlP,
        const float* __restrict__ b1m,
        unsigned short* __restrict__ P, unsigned short* __restrict__ Q,
        float* __restrict__ colsum,
        int nNodes, int doCS, int doPre) {
    const int lane = threadIdx.x & 63;
    const int wib  = threadIdx.x >> 6;
    const int quad = lane >> 4, col = lane & 15;
    __shared__ unsigned short sm[4][16 * 136];   // [h|agg] stage, 17408 B
    __shared__ unsigned short tb[4][16 * 72];    // tv tile, then hn tile, 9216 B
    __shared__ unsigned short wB[8192];          // U2 [hi|lo] frags, 16384 B
    __shared__ unsigned short wP[8192];          // W1(l+1) fp16 frags (16), 16384 B
    unsigned short* __restrict__ mt = sm[wib];
    unsigned short* __restrict__ tv = tb[wib];

    // block-cooperative U2 stage (+ W1 fp16-merge if doPre)
    {
        const short8* __restrict__ sH = (const short8*)wh2;
        const short8* __restrict__ sL = (const short8*)wl2;
        short8* __restrict__ dB = (short8*)wB;
        for (int i = threadIdx.x; i < 512; i += 256) {
            dB[i]       = sH[i];
            dB[512 + i] = sL[i];
        }
        if (doPre) {
            const short8* __restrict__ pH = (const short8*)whP;
            const short8* __restrict__ pL = (const short8*)wlP;
            short8* __restrict__ dP = (short8*)wP;
            for (int i = threadIdx.x; i < 1024; i += 256) {
                short8 hi8 = pH[i], lo8 = pL[i], o;
#pragma unroll
                for (int e = 0; e < 8; ++e) {
                    float w = bf2f((unsigned short)hi8[e]) +
                              bf2f((unsigned short)lo8[e]);
                    o[e] = (short)__half_as_ushort(__float2half_rn(w));
                }
                dP[i] = o;
            }
        }
    }
    __syncthreads();

    short8 bh[4][4], bl[4][4];                   // U1, registers
#pragma unroll
    for (int nt = 0; nt < 4; ++nt)
#pragma unroll
        for (int kf = 0; kf < 4; ++kf) {
            LOADFRAG(bh[nt][kf], wh1, nt, 4, kf);
            LOADFRAG(bl[nt][kf], wl1, nt, 4, kf);
        }
    float bv1[4], bv2[4], bvP[4];
#pragma unroll
    for (int nt = 0; nt < 4; ++nt) {
        bv1[nt] = b1[nt * 16 + col];
        bv2[nt] = b2[nt * 16 + col];
        bvP[nt] = b1m[nt * 16 + col];
    }

    float cs0 = 0.f, cs1 = 0.f, cs2 = 0.f, cs3 = 0.f;
    const int nTiles = (nNodes + 15) >> 4;
    const int wid = blockIdx.x * 4 + wib;
    const int nw  = gridDim.x * 4;
    for (int tile = wid; tile < nTiles; tile += nw) {
        const int base = tile * 16;
        // stage [h|agg] -> bf16 LDS
#pragma unroll
        for (int j = 0; j < 16; ++j) {
            int row = min(base + j, nNodes - 1);
            mt[j * 136 + lane]      = f2bf(h[(size_t)row * 64 + lane]);
            mt[j * 136 + 64 + lane] = f2bf(agg[(size_t)row * 64 + lane]);
        }
        __builtin_amdgcn_s_waitcnt(0);   // drains vmcnt too -> safe to zero agg
#pragma unroll
        for (int j = 0; j < 16; ++j) {
            int row = base + j;
            if (row < nNodes) agg[(size_t)row * 64 + lane] = 0.f;
        }
        short8 a[4];
#pragma unroll
        for (int kf = 0; kf < 4; ++kf)
            a[kf] = *(const short8*)&mt[col * 136 + kf * 32 + quad * 8];
        // stage 1: U1 MFMA -> relu -> bf16 tv tile in LDS
#pragma unroll
        for (int nt = 0; nt < 4; ++nt) {
            float4v c = {0.f, 0.f, 0.f, 0.f};
#pragma unroll
            for (int kf = 0; kf < 4; ++kf) c = MFMA16(a[kf], bh[nt][kf], c);
#pragma unroll
            for (int kf = 0; kf < 4; ++kf) c = MFMA16(a[kf], bl[nt][kf], c);
#pragma unroll
            for (int r = 0; r < 4; ++r)
                tv[(quad * 4 + r) * 72 + nt * 16 + col] =
                    f2bf(fmaxf(c[r] + bv1[nt], 0.f));
        }
        __builtin_amdgcn_s_waitcnt(0);   // wave-local LDS drain
        short8 a0 = *(const short8*)&tv[col * 72 + quad * 8];
        short8 a1 = *(const short8*)&tv[col * 72 + 32 + quad * 8];
        // stage 2: U2 MFMA (weights from block LDS) -> relu -> RMW h;
        // write hn as FP16 back into tv tile (consumed) for the fused pre.
#pragma unroll
        for (int nt = 0; nt < 4; ++nt) {
            const short8 h0 = *(const short8*)&wB[((nt * 2 + 0) * 64 + lane) * 8];
            const short8 h1 = *(const short8*)&wB[((nt * 2 + 1) * 64 + lane) * 8];
            const short8 l0 = *(const short8*)&wB[4096 + ((nt * 2 + 0) * 64 + lane) * 8];
            const short8 l1 = *(const short8*)&wB[4096 + ((nt * 2 + 1) * 64 + lane) * 8];
            float4v c = {0.f, 0.f, 0.f, 0.f};
            c = MFMA16(a0, h0, c);
            c = MFMA16(a1, h1, c);
            c = MFMA16(a0, l0, c);
            c = MFMA16(a1, l1, c);
#pragma unroll
            for (int r = 0; r < 4; ++r) {
                int row = base + quad * 4 + r;
                if (row < nNodes) {
                    float* hp = &h[(size_t)row * 64 + nt * 16 + col];
                    float hn = *hp + fmaxf(c[r] + bv2[nt], 0.f);
                    *hp = hn;
                    if (doPre)
                        tv[(quad * 4 + r) * 72 + nt * 16 + col] =
                            __half_as_ushort(__float2half_rn(hn));
                    cs0 += (nt == 0) ? hn : 0.f;
                    cs1 += (nt == 1) ? hn : 0.f;
                    cs2 += (nt == 2) ? hn : 0.f;
                    cs3 += (nt == 3) ? hn : 0.f;
                }
            }
        }
        // stage 3 (fused k_pre): P/Q = hn @ W1(l+1), fp16 A/B, fp16 outputs
        if (doPre) {
            __builtin_amdgcn_s_waitcnt(0);   // wave-local LDS drain
            short8 p0 = *(const short8*)&tv[col * 72 + quad * 8];
            short8 p1 = *(const short8*)&tv[col * 72 + 32 + quad * 8];
#pragma unroll
            for (int nt = 0; nt < 8; ++nt) {
                const short8 f0 = *(const short8*)&wP[((nt * 2 + 0) * 64 + lane) * 8];
                const short8 f1 = *(const short8*)&wP[((nt * 2 + 1) * 64 + lane) * 8];
                float4v c = {0.f, 0.f, 0.f, 0.f};
                c = MFMA16H(p0, f0, c);
                c = MFMA16H(p1, f1, c);
                unsigned short* __restrict__ outp = (nt < 4) ? P : Q;
                const int nc = (nt & 3) * 16 + col;
                const float badd = (nt < 4) ? bvP[nt & 3] : 0.f;
#pragma unroll
                for (int r = 0; r < 4; ++r) {
                    int row = base + quad * 4 + r;
                    if (row < nNodes)
                        outp[(size_t)row * 64 + nc] =
                            __half_as_ushort(__float2half_rn(c[r] + badd));
                }
            }
        }
    }
    if (doCS) {
        cs0 += __shfl_xor(cs0, 16); cs0 += __shfl_xor(cs0, 32);
        cs1 += __shfl_xor(cs1, 16); cs1 += __shfl_xor(cs1, 32);
        cs2 += __shfl_xor(cs2, 16); cs2 += __shfl_xor(cs2, 32);
        cs3 += __shfl_xor(cs3, 16); cs3 += __shfl_xor(cs3, 32);
        const float tot = (quad == 0) ? cs0 : (quad == 1) ? cs1
                        : (quad == 2) ? cs2 : cs3;
        atomicAdd(&colsum[lane], tot);   // lane == quad*16+col
    }
}

// ---------------- edge kernel: fp16x2 packed m1, 32-edge batches ----------------
// R17: W2 hi/lo B-frags in block-shared LDS (fp16): hi ushort 0, lo 4096.
// R26-R28: m1 loop = 16 iters x 2 rows (half-wave/row) with v_pk_f16 ops;
//      row metadata via readlane-pair + cndmask (NO bpermute).
// R29: edge data from 32B packed records; ea table = 4 coalesced dword
//      loads of the record block (256 entries; int slots never read).
#define EST 72   // fp16 elems per staged m1 row (144B stride, bank-spread)

__global__ __launch_bounds__(256, 4) void k_edge(const unsigned short* __restrict__ P,
        const unsigned short* __restrict__ Q, const float* __restrict__ rec,
        const float* __restrict__ w1e,
        const unsigned short* __restrict__ wh, const unsigned short* __restrict__ wl,
        const float* __restrict__ b2,
        float* __restrict__ agg, int nEdges) {
    const int lane = threadIdx.x & 63;
    const int wib  = threadIdx.x >> 6;
    const int wid  = blockIdx.x * 4 + wib;
    const int nw   = gridDim.x * 4;
    const int quad = lane >> 4;
    const int col  = lane & 15;
    const int li   = lane & 31;
    const int hs   = lane >> 5;          // half-wave select (0/1)

    __shared__ unsigned short m1b[4][32 * EST];   // 18432 B (fp16 m1)
    __shared__ unsigned int   eab[4][256];        //  4096 B (half2-bcast rec block)
    __shared__ unsigned short wB[8192];           // 16384 B: [hi | lo] fp16 frags
    unsigned short* __restrict__ mt  = m1b[wib];
    unsigned int*   __restrict__ eaw = eab[wib];

    // block-cooperative weight stage: 8 frags hi + 8 frags lo = 1024 short8
    {
        const short8* __restrict__ sH = (const short8*)wh;
        const short8* __restrict__ sL = (const short8*)wl;
        short8* __restrict__ dB = (short8*)wB;
        for (int i = threadIdx.x; i < 512; i += 256) {
            dB[i]       = sH[i];
            dB[512 + i] = sL[i];
        }
    }
    __syncthreads();

    // W1e column-pair weights as half2 (cols 2li, 2li+1)
    __half2 w1ec2[6];
#pragma unroll
    for (int jj = 0; jj < 6; ++jj)
        w1ec2[jj] = __halves2half2(__float2half_rn(w1e[jj * 64 + 2 * li]),
                                   __float2half_rn(w1e[jj * 64 + 2 * li + 1]));

    float b2v[4];
#pragma unroll
    for (int nt = 0; nt < 4; ++nt) b2v[nt] = b2[nt * 16 + col];

    // contiguous chunk per wave: dst-sorted records -> P/agg locality
    const int nBatch = (nEdges + 31) >> 5;
    const int per = nBatch / nw, rem = nBatch % nw;
    const int btLo = wid * per + min(wid, rem);
    const int btHi = btLo + per + (wid < rem ? 1 : 0);

    const int* __restrict__ reci = (const int*)rec;

    for (int bt = btLo; bt < btHi; ++bt) {
        const int base = __builtin_amdgcn_readfirstlane(bt << 5);
        const int gidx = min(base + li, nEdges - 1);
        const int vsj = reci[(size_t)gidx * 8];       // row li's src
        const int vdj = reci[(size_t)gidx * 8 + 1];   // row li's dst (lanes 32-63 dup)
        const int vprev = __shfl_up(vdj, 1);
        unsigned long long bmask =
            __ballot(lane < 32 && (li == 0 || vdj != vprev));
        bmask |= (1ull << 32) | 1ull;

        // ---- record block -> half2-broadcast LDS table (4 coalesced loads) ----
        const int fMax = nEdges * 8 - 1;
        const int fBase = base * 8;
#pragma unroll
        for (int k = 0; k < 4; ++k)
            eaw[k * 64 + lane] =
                h22u(__float2half2_rn(rec[min(fBase + k * 64 + lane, fMax)]));

        // ---- m1: 16 iters x 2 rows, fp16x2 column pairs ----
        // row select via readlane-pair (compile-time lanes) + cndmask.
#pragma unroll
        for (int j = 0; j < 16; ++j) {
            const int d0 = __builtin_amdgcn_readlane(vdj, 2 * j);
            const int d1 = __builtin_amdgcn_readlane(vdj, 2 * j + 1);
            const int s0 = __builtin_amdgcn_readlane(vsj, 2 * j);
            const int s1 = __builtin_amdgcn_readlane(vsj, 2 * j + 1);
            const int d = hs ? d1 : d0;
            const int s = hs ? s1 : s0;
            const int rsel = 2 * j + hs;               // this half-wave's row
            const unsigned int p2 = *(const unsigned int*)&P[(size_t)d * 64 + 2 * li];
            const unsigned int q2 = *(const unsigned int*)&Q[(size_t)s * 64 + 2 * li];
            __half2 t = __hadd2(u2h2(p2), u2h2(q2));
#pragma unroll
            for (int jj = 0; jj < 6; ++jj) {
                // record rsel, float slot 2+jj -> table index rsel*8 + 2 + jj
                const unsigned int eu = eaw[16 * j + 8 * hs + 2 + jj];
                t = __hfma2(u2h2(eu), w1ec2[jj], t);
            }
            *(unsigned int*)((char*)mt + rsel * (EST * 2) + li * 4) = pkmax0(h22u(t));
        }
        __builtin_amdgcn_s_waitcnt(0);   // wave-local LDS drain

        short8 a00 = *(const short8*)&mt[col * EST + quad * 8];
        short8 a01 = *(const short8*)&mt[col * EST + 32 + quad * 8];
        short8 a10 = *(const short8*)&mt[(16 + col) * EST + quad * 8];
        short8 a11 = *(const short8*)&mt[(16 + col) * EST + 32 + quad * 8];

        // m2 (fp16 MFMA, same frag layout) for both 16-row tiles
        float4v m2v[2][4];
#pragma unroll
        for (int nt = 0; nt < 4; ++nt) {
            const short8 h0 = *(const short8*)&wB[((nt * 2 + 0) * 64 + lane) * 8];
            const short8 h1 = *(const short8*)&wB[((nt * 2 + 1) * 64 + lane) * 8];
            const short8 l0 = *(const short8*)&wB[4096 + ((nt * 2 + 0) * 64 + lane) * 8];
            const short8 l1 = *(const short8*)&wB[4096 + ((nt * 2 + 1) * 64 + lane) * 8];
            float4v c0 = {0.f, 0.f, 0.f, 0.f};
            float4v c1 = {0.f, 0.f, 0.f, 0.f};
            c0 = MFMA16H(a00, h0, c0);
            c0 = MFMA16H(a01, h1, c0);
            c0 = MFMA16H(a00, l0, c0);
            c0 = MFMA16H(a01, l1, c0);
            c1 = MFMA16H(a10, h0, c1);
            c1 = MFMA16H(a11, h1, c1);
            c1 = MFMA16H(a10, l0, c1);
            c1 = MFMA16H(a11, l1, c1);
#pragma unroll
            for (int r = 0; r < 4; ++r) {
                const bool v0 = base + (quad * 4 + r) < nEdges;
                const bool v1 = base + 16 + (quad * 4 + r) < nEdges;
                m2v[0][nt][r] = v0 ? fmaxf(c0[r] + b2v[nt], 0.f) : 0.f;
                m2v[1][nt][r] = v1 ? fmaxf(c1[r] + b2v[nt], 0.f) : 0.f;
            }
        }

        // ---- segmented reduce + one coalesced atomic per segment ----
        int r0 = 0;
        while (r0 < 32) {
            const int nid = __builtin_amdgcn_readlane(vdj, r0);
            const int r1 = r0 + 1 + (int)__builtin_ctzll(bmask >> (r0 + 1));
            float s0 = 0.f, s1 = 0.f, s2 = 0.f, s3 = 0.f;
#pragma unroll
            for (int t = 0; t < 2; ++t)
#pragma unroll
                for (int r = 0; r < 4; ++r) {
                    const int R = t * 16 + quad * 4 + r;
                    const bool in = (R >= r0) && (R < r1);
                    s0 += in ? m2v[t][0][r] : 0.f;
                    s1 += in ? m2v[t][1][r] : 0.f;
                    s2 += in ? m2v[t][2][r] : 0.f;
                    s3 += in ? m2v[t][3][r] : 0.f;
                }
            s0 += __shfl_xor(s0, 16); s0 += __shfl_xor(s0, 32);
            s1 += __shfl_xor(s1, 16); s1 += __shfl_xor(s1, 32);
            s2 += __shfl_xor(s2, 16); s2 += __shfl_xor(s2, 32);
            s3 += __shfl_xor(s3, 16); s3 += __shfl_xor(s3, 32);
            const float tot = (quad == 0) ? s0 : (quad == 1) ? s1
                            : (quad == 2) ? s2 : s3;
            atomicAdd(&agg[(size_t)nid * 64 + lane], tot);
            r0 = r1;
        }
    }
}

__global__ void k_out(const float* __restrict__ colsum, const float* __restrict__ pw,
                      const float* __restrict__ pb, float* __restrict__ out, int nNodes) {
    const int lane = threadIdx.x;
    float v = colsum[lane] * pw[lane];
#pragma unroll
    for (int off = 32; off; off >>= 1) v += __shfl_down(v, off);
    if (lane == 0) out[0] = v + (float)nNodes * pb[0];
}

extern "C" void kernel_launch(void* const* d_in, const int* in_sizes, int n_in,
                              void* d_out, int out_size, void* d_ws, size_t ws_size,
                              hipStream_t stream) {
    const float* x     = (const float*)d_in[0];
    const int*   ei    = (const int*)d_in[1];
    const float* ea    = (const float*)d_in[2];
    const float* lin_w = (const float*)d_in[3];
    const float* lin_b = (const float*)d_in[4];
    const float* mw1   = (const float*)d_in[5];
    const float* mb1   = (const float*)d_in[6];
    const float* mw2   = (const float*)d_in[7];
    const float* mb2   = (const float*)d_in[8];
    const float* uw1   = (const float*)d_in[9];
    const float* ub1   = (const float*)d_in[10];
    const float* uw2   = (const float*)d_in[11];
    const float* ub2   = (const float*)d_in[12];
    const float* pw    = (const float*)d_in[13];
    const float* pb    = (const float*)d_in[14];

    const int nNodes = in_sizes[0] / 128;
    const int nEdges = in_sizes[1] / 2;
    const int* src = ei;            // edge_index[0]
    const int* dst = ei + nEdges;   // edge_index[1]

    // workspace layout (floats, then ushorts, then ints)
    float* h       = (float*)d_ws;
    float* agg     = h   + (size_t)nNodes * 64;
    float* rec     = agg + (size_t)nNodes * 64;   // 32B packed edge records
    float* colsum  = rec + (size_t)nEdges * 8;
    unsigned short* Pb  = (unsigned short*)(colsum + 64);
    unsigned short* Qb  = Pb + (size_t)nNodes * 64;
    unsigned short* wpH = Qb + (size_t)nNodes * 64;
    unsigned short* wpL = wpH + WP_TOTAL;
    int*   deg     = (int*)(wpL + WP_TOTAL);
    int*   cursor  = deg + nNodes;
    int*   local   = cursor + nNodes;
    int*   bsum    = local + nNodes;

    const int NB_T    = 392;                     // node-GEMM tiles: ~2/wave (measured sweet spot)
    const int NB_EDGE = 2048;
    const int NB_FLAT = (nEdges + 255) / 256;
    const int NB_SCAN = (nNodes + 255) / 256;

    // ---- one-time: CSR build + weight prep ----
    hipMemsetAsync(deg, 0, (size_t)nNodes * sizeof(int), stream);
    hipMemsetAsync(colsum, 0, 64 * sizeof(float), stream);
    hipMemsetAsync(agg, 0, (size_t)nNodes * 64 * sizeof(float), stream);
    k_hist<<<NB_FLAT, 256, 0, stream>>>(dst, deg, nEdges);
    k_scan1<<<NB_SCAN, 256, 0, stream>>>(deg, local, bsum, nNodes);
    k_scan2<<<1, 256, 0, stream>>>(bsum, NB_SCAN);
    k_scan3<<<NB_SCAN, 256, 0, stream>>>(local, bsum, cursor, nNodes);
    k_scatter<<<NB_FLAT, 256, 0, stream>>>(src, dst, ea, cursor, rec, nEdges);
    k_wprep<<<(WP_TOTAL + 255) / 256, 256, 0, stream>>>(lin_w, mw1, mw2, uw1, uw2, wpH, wpL);

    k_in<<<NB_T, 256, 0, stream>>>(x, wpH + OFF_IN, wpL + OFF_IN, lin_b, h, nNodes);
    k_pre<<<NB_T, 256, 0, stream>>>(h, wpH + OFF_PRE(0), wpL + OFF_PRE(0),
        mb1, Pb, Qb, nNodes);   // layer 0 only; layers 1-3 fused into k_upd

    for (int l = 0; l < 4; ++l) {
        const int lp = (l < 3) ? (l + 1) : 3;    // W1(l+1) for fused pre (unused l=3)
        k_edge<<<NB_EDGE, 256, 0, stream>>>(Pb, Qb, rec,
            mw1 + (size_t)l * 134 * 64 + 128 * 64,
            wpH + OFF_MW2(l), wpL + OFF_MW2(l), mb2 + l * 64, agg, nEdges);
        k_upd<<<NB_T, 256, 0, stream>>>(h, agg,
            wpH + OFF_UW1(l), wpL + OFF_UW1(l), ub1 + l * 64,
            wpH + OFF_UW2(l), wpL + OFF_UW2(l), ub2 + l * 64,
            wpH + OFF_PRE(lp), wpL + OFF_PRE(lp),
            (l < 3) ? (mb1 + (l + 1) * 64) : mb1,
            Pb, Qb, colsum, nNodes, (l == 3) ? 1 : 0, (l < 3) ? 1 : 0);
    }

    k_out<<<1, 64, 0, stream>>>(colsum, pw, pb, (float*)d_out, nNodes);
}

// Round 20
// 516.542 us; speedup vs baseline: 1.1584x; 1.0186x over previous
//
#include <hip/hip_runtime.h>
#include <hip/hip_fp16.h>

// MPNN on MI355X.
//
// Algebra: msg layer-1 is linear before its relu:
//   m1 = relu(P[dst] + Q[src] + ea@W1e + b1), P = h@W1[0:64]+b1, Q = h@W1[64:128]
// R3: m2 GEMM via MFMA. R4: dst-sorted CSR, consumer-side aggregation.
// R5-R7: flat 32-edge batches, readlane metadata, ballot segment mask,
//     per-segment coalesced atomic. R12: fragment-layout weights.
// R17 (WIN, 642us): k_edge weight B-frags -> block-shared LDS.
// R26-R28 (WIN, 561.8us): fp16x2 packed m1; readlane-pair row select.
// R29 (WIN, 552.2us): k_scatter 32B packed records (5x write amp killed).
// R30 (REGRESSION): 1-tile/wave grids lose (prologue doubling). NB_T=392.
// R31 (WIN, 538.0us): k_upd1+k_upd2 fused (tv round-trip + one pass gone).
// R32 (NaN) -> R33 (WIN, 526.1us): k_pre(l+1) fused into k_upd; W1(l+1)
//     staged as single fp16 frags (16 frags = exactly 8192 ushorts).
//     k_upd 53.7us absorbs pre for +0.8us; 3 dispatches + 3 h passes gone.
// R34 (RETRY; prior attempt = container infra failure, kernel never ran):
//     k_upd cross-tile prefetch. k_upd is 41% of total at 9.6% occ, 90%
//     stalled; each wave runs ~2 tiles back-to-back paying the full
//     32-load stage round twice. Prefetch next tile's h/agg into 32 f32
//     regs (static indexing; VGPR 112->~145 < 168 headroom, occupancy
//     unchanged: LDS/grid caps bind), issue right after current LDS
//     write; replace full waitcnt(0)s with lgkm-only (+sched_barrier,
//     guide rule 18) so the prefetch rides under all 3 MFMA stages.
//     Tiles are wave-owned & disjoint -> no cross-wave hazards.

typedef __attribute__((ext_vector_type(8))) short short8;
typedef __attribute__((ext_vector_type(4))) float float4v;

__device__ __forceinline__ unsigned short f2bf(float f) {
    unsigned int u = __float_as_uint(f);
    unsigned int r = u + 0x7fff + ((u >> 16) & 1);   // RTNE
    return (unsigned short)(r >> 16);
}
__device__ __forceinline__ float bf2f(unsigned short u) {
    return __uint_as_float(((unsigned int)u) << 16);
}
__device__ __forceinline__ __half2 u2h2(unsigned int u) {
    union { unsigned int u; __half2 h; } c; c.u = u; return c.h;
}
__device__ __forceinline__ unsigned int h22u(__half2 h) {
    union { unsigned int u; __half2 h; } c; c.h = h; return c.u;
}
// ROCm 7.2 lacks __hmax2; gfx950 has v_pk_max_f16 — emit it directly.
__device__ __forceinline__ unsigned int pkmax0(unsigned int a) {
    unsigned int r;
    asm("v_pk_max_f16 %0, %1, %2" : "=v"(r) : "v"(a), "v"(0u));
    return r;
}
// lgkm-only drain: leaves vmcnt (prefetch) in flight. sched_barrier per
// guide rule 18 (hipcc can hoist reg-only MFMA past inline-asm waits).
__device__ __forceinline__ void lgkm_drain() {
    asm volatile("s_waitcnt lgkmcnt(0)" ::: "memory");
    __builtin_amdgcn_sched_barrier(0);
}

#define MFMA16(a, b, c)  __builtin_amdgcn_mfma_f32_16x16x32_bf16(a, b, c, 0, 0, 0)
#define MFMA16H(a, b, c) __builtin_amdgcn_mfma_f32_16x16x32_f16(a, b, c, 0, 0, 0)

struct bfpair { short hi, lo; };
__device__ __forceinline__ bfpair wsplit(float wv) {
    bfpair p;
    unsigned short h = f2bf(wv);
    float hf = __uint_as_float(((unsigned int)h) << 16);
    p.hi = (short)h;
    p.lo = (short)f2bf(wv - hf);
    return p;
}

// fragment-layout weight prep offsets (ushort elements)
#define WP_TOTAL 106496
#define OFF_IN   0
#define OFF_PRE(l)  (8192  + (l) * 8192)
#define OFF_MW2(l)  (40960 + (l) * 4096)
#define OFF_UW1(l)  (57344 + (l) * 8192)
#define OFF_UW2(l)  (90112 + (l) * 4096)

// ---------------- weight prep: fp32 -> hi/lo bf16 (fp16 for MW2) ----------------
__global__ __launch_bounds__(256) void k_wprep(const float* __restrict__ lin_w,
        const float* __restrict__ mw1, const float* __restrict__ mw2,
        const float* __restrict__ uw1, const float* __restrict__ uw2,
        unsigned short* __restrict__ H, unsigned short* __restrict__ L) {
    const int tid = blockIdx.x * 256 + threadIdx.x;
    if (tid >= WP_TOTAL) return;
    float val;
    if (tid < 8192) {                                  // lin_in_w: KF=4, NT=4
        int rem = tid;
        int nt = rem >> 11, kf = (rem >> 9) & 3;
        int lane = (rem >> 3) & 63, j = rem & 7;
        int k = kf * 32 + (lane >> 4) * 8 + j;
        val = lin_w[k * 64 + nt * 16 + (lane & 15)];
    } else if (tid < 40960) {                          // msg_w1[0:128]: KF=2, NT=8
        int t = tid - 8192, layer = t >> 13, rem = t & 8191;
        int nt = rem >> 10, kf = (rem >> 9) & 1;
        int lane = (rem >> 3) & 63, j = rem & 7;
        int k = kf * 32 + (lane >> 4) * 8 + j;
        const float* w1 = mw1 + (size_t)layer * 134 * 64;
        val = (nt < 4) ? w1[k * 64 + nt * 16 + (lane & 15)]
                       : w1[(64 + k) * 64 + (nt - 4) * 16 + (lane & 15)];
    } else if (tid < 57344) {                          // msg_w2: KF=2, NT=4 (fp16!)
        int t = tid - 40960, layer = t >> 12, rem = t & 4095;
        int nt = rem >> 10, kf = (rem >> 9) & 1;
        int lane = (rem >> 3) & 63, j = rem & 7;
        int k = kf * 32 + (lane >> 4) * 8 + j;
        val = mw2[(size_t)layer * 4096 + k * 64 + nt * 16 + (lane & 15)];
    } else if (tid < 90112) {                          // upd_w1: KF=4, NT=4
        int t = tid - 57344, layer = t >> 13, rem = t & 8191;
        int nt = rem >> 11, kf = (rem >> 9) & 3;
        int lane = (rem >> 3) & 63, j = rem & 7;
        int k = kf * 32 + (lane >> 4) * 8 + j;
        val = uw1[(size_t)layer * 8192 + k * 64 + nt * 16 + (lane & 15)];
    } else {                                           // upd_w2: KF=2, NT=4
        int t = tid - 90112, layer = t >> 12, rem = t & 4095;
        int nt = rem >> 10, kf = (rem >> 9) & 1;
        int lane = (rem >> 3) & 63, j = rem & 7;
        int k = kf * 32 + (lane >> 4) * 8 + j;
        val = uw2[(size_t)layer * 4096 + k * 64 + nt * 16 + (lane & 15)];
    }
    if (tid >= 40960 && tid < 57344) {                 // fp16 hi/lo for k_edge m2
        __half hh = __float2half_rn(val);
        float hf = __half2float(hh);
        __half hl = __float2half_rn(val - hf);
        H[tid] = __half_as_ushort(hh);
        L[tid] = __half_as_ushort(hl);
    } else {
        bfpair p = wsplit(val);
        H[tid] = (unsigned short)p.hi;
        L[tid] = (unsigned short)p.lo;
    }
}

#define LOADFRAG(dst, arr, nt, KF, kf) \
    dst = *(const short8*)&arr[((((nt) * (KF)) + (kf)) * 64 + lane) * 8]

// ---------------- CSR build (dst bins) ----------------
__global__ __launch_bounds__(256) void k_hist(const int* __restrict__ dst,
        int* __restrict__ deg, int nEdges) {
    int e = blockIdx.x * blockDim.x + threadIdx.x;
    if (e < nEdges) atomicAdd(&deg[dst[e]], 1);
}

__global__ __launch_bounds__(256) void k_scan1(const int* __restrict__ deg,
        int* __restrict__ local, int* __restrict__ bsum, int nNodes) {
    __shared__ int sm[256];
    const int t = threadIdx.x;
    const int n = blockIdx.x * 256 + t;
    int v = (n < nNodes) ? deg[n] : 0;
    sm[t] = v;
    __syncthreads();
    for (int off = 1; off < 256; off <<= 1) {
        int u = (t >= off) ? sm[t - off] : 0;
        __syncthreads();
        sm[t] += u;
        __syncthreads();
    }
    if (n < nNodes) local[n] = sm[t] - v;
    if (t == 255) bsum[blockIdx.x] = sm[255];
}

__global__ __launch_bounds__(256) void k_scan2(int* __restrict__ bsum, int nB) {
    __shared__ int sm[256];
    const int t = threadIdx.x;
    int v = (t < nB) ? bsum[t] : 0;
    sm[t] = v;
    __syncthreads();
    for (int off = 1; off < 256; off <<= 1) {
        int u = (t >= off) ? sm[t - off] : 0;
        __syncthreads();
        sm[t] += u;
        __syncthreads();
    }
    if (t < nB) bsum[t] = sm[t] - v;
}

__global__ __launch_bounds__(256) void k_scan3(const int* __restrict__ local,
        const int* __restrict__ bsum, int* __restrict__ cursor, int nNodes) {
    int n = blockIdx.x * 256 + threadIdx.x;
    if (n < nNodes) cursor[n] = bsum[blockIdx.x] + local[n];
}

// R29: one 32B packed record per edge: {src, dst, ea[0..5]}, 2x float4.
__global__ __launch_bounds__(256) void k_scatter(const int* __restrict__ src,
        const int* __restrict__ dst, const float* __restrict__ ea,
        int* __restrict__ cursor, float* __restrict__ rec, int nEdges) {
    int e = blockIdx.x * blockDim.x + threadIdx.x;
    if (e < nEdges) {
        int d = dst[e];
        int s = src[e];
        int pos = atomicAdd(&cursor[d], 1);
        const float* p = ea + (size_t)e * 6;
        float4 lo, hi;
        lo.x = __int_as_float(s);
        lo.y = __int_as_float(d);
        lo.z = p[0];
        lo.w = p[1];
        hi.x = p[2];
        hi.y = p[3];
        hi.z = p[4];
        hi.w = p[5];
        float4* q = (float4*)(rec + (size_t)pos * 8);
        q[0] = lo;
        q[1] = hi;
    }
}

// ---------------- node-side MFMA GEMM kernels ----------------
// A-frag: A[m=col][k=quad*8+j]; C: col=lane&15, row=quad*4+reg (verified).

// h = x @ Win + b   (K=128, N=64)
__global__ __launch_bounds__(256) void k_in(const float* __restrict__ x,
        const unsigned short* __restrict__ wh, const unsigned short* __restrict__ wl,
        const float* __restrict__ bia, float* __restrict__ h, int nNodes) {
    const int lane = threadIdx.x & 63;
    const int wib  = threadIdx.x >> 6;
    const int quad = lane >> 4, col = lane & 15;
    __shared__ unsigned short sm[4][16 * 136];
    unsigned short* __restrict__ mt = sm[wib];

    short8 bh[4][4], bl[4][4];
#pragma unroll
    for (int nt = 0; nt < 4; ++nt)
#pragma unroll
        for (int kf = 0; kf < 4; ++kf) {
            LOADFRAG(bh[nt][kf], wh, nt, 4, kf);
            LOADFRAG(bl[nt][kf], wl, nt, 4, kf);
        }
    float bv[4];
#pragma unroll
    for (int nt = 0; nt < 4; ++nt) bv[nt] = bia[nt * 16 + col];

    const int nTiles = (nNodes + 15) >> 4;
    const int wid = blockIdx.x * 4 + wib;
    const int nw  = gridDim.x * 4;
    for (int tile = wid; tile < nTiles; tile += nw) {
        const int base = tile * 16;
#pragma unroll
        for (int j = 0; j < 16; ++j) {
            int row = min(base + j, nNodes - 1);
            mt[j * 136 + lane]      = f2bf(x[(size_t)row * 128 + lane]);
            mt[j * 136 + 64 + lane] = f2bf(x[(size_t)row * 128 + 64 + lane]);
        }
        __builtin_amdgcn_s_waitcnt(0);
        short8 a[4];
#pragma unroll
        for (int kf = 0; kf < 4; ++kf)
            a[kf] = *(const short8*)&mt[col * 136 + kf * 32 + quad * 8];
#pragma unroll
        for (int nt = 0; nt < 4; ++nt) {
            float4v c = {0.f, 0.f, 0.f, 0.f};
#pragma unroll
            for (int kf = 0; kf < 4; ++kf) c = MFMA16(a[kf], bh[nt][kf], c);
#pragma unroll
            for (int kf = 0; kf < 4; ++kf) c = MFMA16(a[kf], bl[nt][kf], c);
#pragma unroll
            for (int r = 0; r < 4; ++r) {
                int row = base + quad * 4 + r;
                if (row < nNodes)
                    h[(size_t)row * 64 + nt * 16 + col] = c[r] + bv[nt];
            }
        }
    }
}

// [P|Q] = h @ [W1[0:64] | W1[64:128]]; P += b1   (K=64, N=128), FP16 outputs
// (standalone: used only for layer 0; layers 1-3 fused into k_upd)
__global__ __launch_bounds__(256) void k_pre(const float* __restrict__ h,
        const unsigned short* __restrict__ wh, const unsigned short* __restrict__ wl,
        const float* __restrict__ b1m,
        unsigned short* __restrict__ P, unsigned short* __restrict__ Q,
        int nNodes) {
    const int lane = threadIdx.x & 63;
    const int wib  = threadIdx.x >> 6;
    const int quad = lane >> 4, col = lane & 15;
    __shared__ unsigned short sm[4][16 * 72];
    unsigned short* __restrict__ mt = sm[wib];

    short8 bh[8][2], bl[8][2];
#pragma unroll
    for (int nt = 0; nt < 8; ++nt)
#pragma unroll
        for (int kf = 0; kf < 2; ++kf) {
            LOADFRAG(bh[nt][kf], wh, nt, 2, kf);
            LOADFRAG(bl[nt][kf], wl, nt, 2, kf);
        }
    float bv1[4];
#pragma unroll
    for (int nt = 0; nt < 4; ++nt) bv1[nt] = b1m[nt * 16 + col];

    const int nTiles = (nNodes + 15) >> 4;
    const int wid = blockIdx.x * 4 + wib;
    const int nw  = gridDim.x * 4;
    for (int tile = wid; tile < nTiles; tile += nw) {
        const int base = tile * 16;
#pragma unroll
        for (int j = 0; j < 16; ++j) {
            int row = min(base + j, nNodes - 1);
            mt[j * 72 + lane] = f2bf(h[(size_t)row * 64 + lane]);
        }
        __builtin_amdgcn_s_waitcnt(0);
        short8 a0 = *(const short8*)&mt[col * 72 + quad * 8];
        short8 a1 = *(const short8*)&mt[col * 72 + 32 + quad * 8];
#pragma unroll
        for (int nt = 0; nt < 8; ++nt) {
            float4v c = {0.f, 0.f, 0.f, 0.f};
            c = MFMA16(a0, bh[nt][0], c);
            c = MFMA16(a1, bh[nt][1], c);
            c = MFMA16(a0, bl[nt][0], c);
            c = MFMA16(a1, bl[nt][1], c);
            unsigned short* __restrict__ outp = (nt < 4) ? P : Q;
            const int nc = (nt & 3) * 16 + col;
            const float badd = (nt < 4) ? bv1[nt & 3] : 0.f;
#pragma unroll
            for (int r = 0; r < 4; ++r) {
                int row = base + quad * 4 + r;
                if (row < nNodes)
                    outp[(size_t)row * 64 + nc] =
                        __half_as_ushort(__float2half_rn(c[r] + badd));
            }
        }
    }
}

// R31/R33/R34 fused update: tv = relu([h|agg]@U1+b1); h += relu(tv@U2+b2);
// zero agg; optional colsum; if doPre: P/Q = hn @ W1(l+1) (+b1) fp16.
// U1 in regs, U2 in block LDS (bf16 hi/lo), W1(l+1) in block LDS fp16.
// R34: next-tile h/agg prefetched into regs; lgkm-only waits keep the
// prefetch in flight under all 3 MFMA stages.
__global__ __launch_bounds__(256) void k_upd(float* __restrict__ h,
        float* __restrict__ agg,
        const unsigned short* __restrict__ wh1, const unsigned short* __restrict__ wl1,
        const float* __restrict__ b1,
        const unsigned short* __restrict__ wh2, const unsigned short* __restrict__ wl2,
        const float* __restrict__ b2,
        const unsigned short* __restrict__ whP, const unsigned short* __restrict__ wlP,
        const float* __restrict__ b1m,
        unsigned short* __restrict__ P, unsigned short* __restrict__ Q,
        float* __restrict__ colsum,
        int nNodes, int doCS, int doPre) {
    const int lane = threadIdx.x & 63;
    const int wib  = threadIdx.x >> 6;
    const int quad = lane >> 4, col = lane & 15;
    __shared__ unsigned short sm[4][16 * 136];   // [h|agg] stage, 17408 B
    __shared__ unsigned short tb[4][16 * 72];    // tv tile, then hn tile, 9216 B
    __shared__ unsigned short wB[8192];          // U2 [hi|lo] frags, 16384 B
    __shared__ unsigned short wP[8192];          // W1(l+1) fp16 frags (16), 16384 B
    unsigned short* __restrict__ mt = sm[wib];
    unsigned short* __restrict__ tv = tb[wib];

    // block-cooperative U2 stage (+ W1 fp16-merge if doPre)
    {
        const short8* __restrict__ sH = (const short8*)wh2;
        const short8* __restrict__ sL = (const short8*)wl2;
        short8* __restrict__ dB = (short8*)wB;
        for (int i = threadIdx.x; i < 512; i += 256) {
            dB[i]       = sH[i];
            dB[512 + i] = sL[i];
        }
        if (doPre) {
            const short8* __restrict__ pH = (const short8*)whP;
            const short8* __restrict__ pL = (const short8*)wlP;
            short8* __restrict__ dP = (short8*)wP;
            for (int i = threadIdx.x; i < 1024; i += 256) {
                short8 hi8 = pH[i], lo8 = pL[i], o;
#pragma unroll
                for (int e = 0; e < 8; ++e) {
                    float w = bf2f((unsigned short)hi8[e]) +
                              bf2f((unsigned short)lo8[e]);
                    o[e] = (short)__half_as_ushort(__float2half_rn(w));
                }
                dP[i] = o;
            }
        }
    }
    __syncthreads();

    short8 bh[4][4], bl[4][4];                   // U1, registers
#pragma unroll
    for (int nt = 0; nt < 4; ++nt)
#pragma unroll
        for (int kf = 0; kf < 4; ++kf) {
            LOADFRAG(bh[nt][kf], wh1, nt, 4, kf);
            LOADFRAG(bl[nt][kf], wl1, nt, 4, kf);
        }
    float bv1[4], bv2[4], bvP[4];
#pragma unroll
    for (int nt = 0; nt < 4; ++nt) {
        bv1[nt] = b1[nt * 16 + col];
        bv2[nt] = b2[nt * 16 + col];
        bvP[nt] = b1m[nt * 16 + col];
    }

    float cs0 = 0.f, cs1 = 0.f, cs2 = 0.f, cs3 = 0.f;
    const int nTiles = (nNodes + 15) >> 4;
    const int wid = blockIdx.x * 4 + wib;
    const int nw  = gridDim.x * 4;

    // R34: prefetch first tile's h/agg into registers
    float hv[16], av[16];
    if (wid < nTiles) {
        const int base = wid * 16;
#pragma unroll
        for (int j = 0; j < 16; ++j) {
            int row = min(base + j, nNodes - 1);
            hv[j] = h[(size_t)row * 64 + lane];
            av[j] = agg[(size_t)row * 64 + lane];
        }
    }

    for (int tile = wid; tile < nTiles; tile += nw) {
        const int base = tile * 16;
        // write staged regs -> bf16 LDS (compiler waits the vm loads here)
#pragma unroll
        for (int j = 0; j < 16; ++j) {
            mt[j * 136 + lane]      = f2bf(hv[j]);
            mt[j * 136 + 64 + lane] = f2bf(av[j]);
        }
        // zero agg for current rows (values already consumed into LDS path)
#pragma unroll
        for (int j = 0; j < 16; ++j) {
            int row = base + j;
            if (row < nNodes) agg[(size_t)row * 64 + lane] = 0.f;
        }
        // issue prefetch for the wave's next tile (stays in flight)
        const int nxt = tile + nw;
        if (nxt < nTiles) {
            const int nb = nxt * 16;
#pragma unroll
            for (int j = 0; j < 16; ++j) {
                int row = min(nb + j, nNodes - 1);
                hv[j] = h[(size_t)row * 64 + lane];
                av[j] = agg[(size_t)row * 64 + lane];
            }
        }
        lgkm_drain();                    // LDS writes visible; vm prefetch live
        short8 a[4];
#pragma unroll
        for (int kf = 0; kf < 4; ++kf)
            a[kf] = *(const short8*)&mt[col * 136 + kf * 32 + quad * 8];
        // stage 1: U1 MFMA -> relu -> bf16 tv tile in LDS
#pragma unroll
        for (int nt = 0; nt < 4; ++nt) {
            float4v c = {0.f, 0.f, 0.f, 0.f};
#pragma unroll
            for (int kf = 0; kf < 4; ++kf) c = MFMA16(a[kf], bh[nt][kf], c);
#pragma unroll
            for (int kf = 0; kf < 4; ++kf) c = MFMA16(a[kf], bl[nt][kf], c);
#pragma unroll
            for (int r = 0; r < 4; ++r)
                tv[(quad * 4 + r) * 72 + nt * 16 + col] =
                    f2bf(fmaxf(c[r] + bv1[nt], 0.f));
        }
        lgkm_drain();
        short8 a0 = *(const short8*)&tv[col * 72 + quad * 8];
        short8 a1 = *(const short8*)&tv[col * 72 + 32 + quad * 8];
        // stage 2: U2 MFMA (weights from block LDS) -> relu -> RMW h;
        // write hn as FP16 back into tv tile (consumed) for the fused pre.
#pragma unroll
        for (int nt = 0; nt < 4; ++nt) {
            const short8 h0 = *(const short8*)&wB[((nt * 2 + 0) * 64 + lane) * 8];
            const short8 h1 = *(const short8*)&wB[((nt * 2 + 1) * 64 + lane) * 8];
            const short8 l0 = *(const short8*)&wB[4096 + ((nt * 2 + 0) * 64 + lane) * 8];
            const short8 l1 = *(const short8*)&wB[4096 + ((nt * 2 + 1) * 64 + lane) * 8];
            float4v c = {0.f, 0.f, 0.f, 0.f};
            c = MFMA16(a0, h0, c);
            c = MFMA16(a1, h1, c);
            c = MFMA16(a0, l0, c);
            c = MFMA16(a1, l1, c);
#pragma unroll
            for (int r = 0; r < 4; ++r) {
                int row = base + quad * 4 + r;
                if (row < nNodes) {
                    float* hp = &h[(size_t)row * 64 + nt * 16 + col];
                    float hn = *hp + fmaxf(c[r] + bv2[nt], 0.f);
                    *hp = hn;
                    if (doPre)
                        tv[(quad * 4 + r) * 72 + nt * 16 + col] =
                            __half_as_ushort(__float2half_rn(hn));
                    cs0 += (nt == 0) ? hn : 0.f;
                    cs1 += (nt == 1) ? hn : 0.f;
                    cs2 += (nt == 2) ? hn : 0.f;
                    cs3 += (nt == 3) ? hn : 0.f;
                }
            }
        }
        // stage 3 (fused k_pre): P/Q = hn @ W1(l+1), fp16 A/B, fp16 outputs
        if (doPre) {
            lgkm_drain();
            short8 p0 = *(const short8*)&tv[col * 72 + quad * 8];
            short8 p1 = *(const short8*)&tv[col * 72 + 32 + quad * 8];
#pragma unroll
            for (int nt = 0; nt < 8; ++nt) {
                const short8 f0 = *(const short8*)&wP[((nt * 2 + 0) * 64 + lane) * 8];
                const short8 f1 = *(const short8*)&wP[((nt * 2 + 1) * 64 + lane) * 8];
                float4v c = {0.f, 0.f, 0.f, 0.f};
                c = MFMA16H(p0, f0, c);
                c = MFMA16H(p1, f1, c);
                unsigned short* __restrict__ outp = (nt < 4) ? P : Q;
                const int nc = (nt & 3) * 16 + col;
                const float badd = (nt < 4) ? bvP[nt & 3] : 0.f;
#pragma unroll
                for (int r = 0; r < 4; ++r) {
                    int row = base + quad * 4 + r;
                    if (row < nNodes)
                        outp[(size_t)row * 64 + nc] =
                            __half_as_ushort(__float2half_rn(c[r] + badd));
                }
            }
        }
    }
    if (doCS) {
        cs0 += __shfl_xor(cs0, 16); cs0 += __shfl_xor(cs0, 32);
        cs1 += __shfl_xor(cs1, 16); cs1 += __shfl_xor(cs1, 32);
        cs2 += __shfl_xor(cs2, 16); cs2 += __shfl_xor(cs2, 32);
        cs3 += __shfl_xor(cs3, 16); cs3 += __shfl_xor(cs3, 32);
        const float tot = (quad == 0) ? cs0 : (quad == 1) ? cs1
                        : (quad == 2) ? cs2 : cs3;
        atomicAdd(&colsum[lane], tot);   // lane == quad*16+col
    }
}

// ---------------- edge kernel: fp16x2 packed m1, 32-edge batches ----------------
// R17: W2 hi/lo B-frags in block-shared LDS (fp16): hi ushort 0, lo 4096.
// R26-R28: m1 loop = 16 iters x 2 rows (half-wave/row) with v_pk_f16 ops;
//      row metadata via readlane-pair + cndmask (NO bpermute).
// R29: edge data from 32B packed records; ea table = 4 coalesced dword
//      loads of the record block (256 entries; int slots never read).
#define EST 72   // fp16 elems per staged m1 row (144B stride, bank-spread)

__global__ __launch_bounds__(256, 4) void k_edge(const unsigned short* __restrict__ P,
        const unsigned short* __restrict__ Q, const float* __restrict__ rec,
        const float* __restrict__ w1e,
        const unsigned short* __restrict__ wh, const unsigned short* __restrict__ wl,
        const float* __restrict__ b2,
        float* __restrict__ agg, int nEdges) {
    const int lane = threadIdx.x & 63;
    const int wib  = threadIdx.x >> 6;
    const int wid  = blockIdx.x * 4 + wib;
    const int nw   = gridDim.x * 4;
    const int quad = lane >> 4;
    const int col  = lane & 15;
    const int li   = lane & 31;
    const int hs   = lane >> 5;          // half-wave select (0/1)

    __shared__ unsigned short m1b[4][32 * EST];   // 18432 B (fp16 m1)
    __shared__ unsigned int   eab[4][256];        //  4096 B (half2-bcast rec block)
    __shared__ unsigned short wB[8192];           // 16384 B: [hi | lo] fp16 frags
    unsigned short* __restrict__ mt  = m1b[wib];
    unsigned int*   __restrict__ eaw = eab[wib];

    // block-cooperative weight stage: 8 frags hi + 8 frags lo = 1024 short8
    {
        const short8* __restrict__ sH = (const short8*)wh;
        const short8* __restrict__ sL = (const short8*)wl;
        short8* __restrict__ dB = (short8*)wB;
        for (int i = threadIdx.x; i < 512; i += 256) {
            dB[i]       = sH[i];
            dB[512 + i] = sL[i];
        }
    }
    __syncthreads();

    // W1e column-pair weights as half2 (cols 2li, 2li+1)
    __half2 w1ec2[6];
#pragma unroll
    for (int jj = 0; jj < 6; ++jj)
        w1ec2[jj] = __halves2half2(__float2half_rn(w1e[jj * 64 + 2 * li]),
                                   __float2half_rn(w1e[jj * 64 + 2 * li + 1]));

    float b2v[4];
#pragma unroll
    for (int nt = 0; nt < 4; ++nt) b2v[nt] = b2[nt * 16 + col];

    // contiguous chunk per wave: dst-sorted records -> P/agg locality
    const int nBatch = (nEdges + 31) >> 5;
    const int per = nBatch / nw, rem = nBatch % nw;
    const int btLo = wid * per + min(wid, rem);
    const int btHi = btLo + per + (wid < rem ? 1 : 0);

    const int* __restrict__ reci = (const int*)rec;

    for (int bt = btLo; bt < btHi; ++bt) {
        const int base = __builtin_amdgcn_readfirstlane(bt << 5);
        const int gidx = min(base + li, nEdges - 1);
        const int vsj = reci[(size_t)gidx * 8];       // row li's src
        const int vdj = reci[(size_t)gidx * 8 + 1];   // row li's dst (lanes 32-63 dup)
        const int vprev = __shfl_up(vdj, 1);
        unsigned long long bmask =
            __ballot(lane < 32 && (li == 0 || vdj != vprev));
        bmask |= (1ull << 32) | 1ull;

        // ---- record block -> half2-broadcast LDS table (4 coalesced loads) ----
        const int fMax = nEdges * 8 - 1;
        const int fBase = base * 8;
#pragma unroll
        for (int k = 0; k < 4; ++k)
            eaw[k * 64 + lane] =
                h22u(__float2half2_rn(rec[min(fBase + k * 64 + lane, fMax)]));

        // ---- m1: 16 iters x 2 rows, fp16x2 column pairs ----
        // row select via readlane-pair (compile-time lanes) + cndmask.
#pragma unroll
        for (int j = 0; j < 16; ++j) {
            const int d0 = __builtin_amdgcn_readlane(vdj, 2 * j);
            const int d1 = __builtin_amdgcn_readlane(vdj, 2 * j + 1);
            const int s0 = __builtin_amdgcn_readlane(vsj, 2 * j);
            const int s1 = __builtin_amdgcn_readlane(vsj, 2 * j + 1);
            const int d = hs ? d1 : d0;
            const int s = hs ? s1 : s0;
            const int rsel = 2 * j + hs;               // this half-wave's row
            const unsigned int p2 = *(const unsigned int*)&P[(size_t)d * 64 + 2 * li];
            const unsigned int q2 = *(const unsigned int*)&Q[(size_t)s * 64 + 2 * li];
            __half2 t = __hadd2(u2h2(p2), u2h2(q2));
#pragma unroll
            for (int jj = 0; jj < 6; ++jj) {
                // record rsel, float slot 2+jj -> table index rsel*8 + 2 + jj
                const unsigned int eu = eaw[16 * j + 8 * hs + 2 + jj];
                t = __hfma2(u2h2(eu), w1ec2[jj], t);
            }
            *(unsigned int*)((char*)mt + rsel * (EST * 2) + li * 4) = pkmax0(h22u(t));
        }
        __builtin_amdgcn_s_waitcnt(0);   // wave-local LDS drain

        short8 a00 = *(const short8*)&mt[col * EST + quad * 8];
        short8 a01 = *(const short8*)&mt[col * EST + 32 + quad * 8];
        short8 a10 = *(const short8*)&mt[(16 + col) * EST + quad * 8];
        short8 a11 = *(const short8*)&mt[(16 + col) * EST + 32 + quad * 8];

        // m2 (fp16 MFMA, same frag layout) for both 16-row tiles
        float4v m2v[2][4];
#pragma unroll
        for (int nt = 0; nt < 4; ++nt) {
            const short8 h0 = *(const short8*)&wB[((nt * 2 + 0) * 64 + lane) * 8];
            const short8 h1 = *(const short8*)&wB[((nt * 2 + 1) * 64 + lane) * 8];
            const short8 l0 = *(const short8*)&wB[4096 + ((nt * 2 + 0) * 64 + lane) * 8];
            const short8 l1 = *(const short8*)&wB[4096 + ((nt * 2 + 1) * 64 + lane) * 8];
            float4v c0 = {0.f, 0.f, 0.f, 0.f};
            float4v c1 = {0.f, 0.f, 0.f, 0.f};
            c0 = MFMA16H(a00, h0, c0);
            c0 = MFMA16H(a01, h1, c0);
            c0 = MFMA16H(a00, l0, c0);
            c0 = MFMA16H(a01, l1, c0);
            c1 = MFMA16H(a10, h0, c1);
            c1 = MFMA16H(a11, h1, c1);
            c1 = MFMA16H(a10, l0, c1);
            c1 = MFMA16H(a11, l1, c1);
#pragma unroll
            for (int r = 0; r < 4; ++r) {
                const bool v0 = base + (quad * 4 + r) < nEdges;
                const bool v1 = base + 16 + (quad * 4 + r) < nEdges;
                m2v[0][nt][r] = v0 ? fmaxf(c0[r] + b2v[nt], 0.f) : 0.f;
                m2v[1][nt][r] = v1 ? fmaxf(c1[r] + b2v[nt], 0.f) : 0.f;
            }
        }

        // ---- segmented reduce + one coalesced atomic per segment ----
        int r0 = 0;
        while (r0 < 32) {
            const int nid = __builtin_amdgcn_readlane(vdj, r0);
            const int r1 = r0 + 1 + (int)__builtin_ctzll(bmask >> (r0 + 1));
            float s0 = 0.f, s1 = 0.f, s2 = 0.f, s3 = 0.f;
#pragma unroll
            for (int t = 0; t < 2; ++t)
#pragma unroll
                for (int r = 0; r < 4; ++r) {
                    const int R = t * 16 + quad * 4 + r;
                    const bool in = (R >= r0) && (R < r1);
                    s0 += in ? m2v[t][0][r] : 0.f;
                    s1 += in ? m2v[t][1][r] : 0.f;
                    s2 += in ? m2v[t][2][r] : 0.f;
                    s3 += in ? m2v[t][3][r] : 0.f;
                }
            s0 += __shfl_xor(s0, 16); s0 += __shfl_xor(s0, 32);
            s1 += __shfl_xor(s1, 16); s1 += __shfl_xor(s1, 32);
            s2 += __shfl_xor(s2, 16); s2 += __shfl_xor(s2, 32);
            s3 += __shfl_xor(s3, 16); s3 += __shfl_xor(s3, 32);
            const float tot = (quad == 0) ? s0 : (quad == 1) ? s1
                            : (quad == 2) ? s2 : s3;
            atomicAdd(&agg[(size_t)nid * 64 + lane], tot);
            r0 = r1;
        }
    }
}

__global__ void k_out(const float* __restrict__ colsum, const float* __restrict__ pw,
                      const float* __restrict__ pb, float* __restrict__ out, int nNodes) {
    const int lane = threadIdx.x;
    float v = colsum[lane] * pw[lane];
#pragma unroll
    for (int off = 32; off; off >>= 1) v += __shfl_down(v, off);
    if (lane == 0) out[0] = v + (float)nNodes * pb[0];
}

extern "C" void kernel_launch(void* const* d_in, const int* in_sizes, int n_in,
                              void* d_out, int out_size, void* d_ws, size_t ws_size,
                              hipStream_t stream) {
    const float* x     = (const float*)d_in[0];
    const int*   ei    = (const int*)d_in[1];
    const float* ea    = (const float*)d_in[2];
    const float* lin_w = (const float*)d_in[3];
    const float* lin_b = (const float*)d_in[4];
    const float* mw1   = (const float*)d_in[5];
    const float* mb1   = (const float*)d_in[6];
    const float* mw2   = (const float*)d_in[7];
    const float* mb2   = (const float*)d_in[8];
    const float* uw1   = (const float*)d_in[9];
    const float* ub1   = (const float*)d_in[10];
    const float* uw2   = (const float*)d_in[11];
    const float* ub2   = (const float*)d_in[12];
    const float* pw    = (const float*)d_in[13];
    const float* pb    = (const float*)d_in[14];

    const int nNodes = in_sizes[0] / 128;
    const int nEdges = in_sizes[1] / 2;
    const int* src = ei;            // edge_index[0]
    const int* dst = ei + nEdges;   // edge_index[1]

    // workspace layout (floats, then ushorts, then ints)
    float* h       = (float*)d_ws;
    float* agg     = h   + (size_t)nNodes * 64;
    float* rec     = agg + (size_t)nNodes * 64;   // 32B packed edge records
    float* colsum  = rec + (size_t)nEdges * 8;
    unsigned short* Pb  = (unsigned short*)(colsum + 64);
    unsigned short* Qb  = Pb + (size_t)nNodes * 64;
    unsigned short* wpH = Qb + (size_t)nNodes * 64;
    unsigned short* wpL = wpH + WP_TOTAL;
    int*   deg     = (int*)(wpL + WP_TOTAL);
    int*   cursor  = deg + nNodes;
    int*   local   = cursor + nNodes;
    int*   bsum    = local + nNodes;

    const int NB_T    = 392;                     // node-GEMM tiles: ~2/wave (measured sweet spot)
    const int NB_EDGE = 2048;
    const int NB_FLAT = (nEdges + 255) / 256;
    const int NB_SCAN = (nNodes + 255) / 256;

    // ---- one-time: CSR build + weight prep ----
    hipMemsetAsync(deg, 0, (size_t)nNodes * sizeof(int), stream);
    hipMemsetAsync(colsum, 0, 64 * sizeof(float), stream);
    hipMemsetAsync(agg, 0, (size_t)nNodes * 64 * sizeof(float), stream);
    k_hist<<<NB_FLAT, 256, 0, stream>>>(dst, deg, nEdges);
    k_scan1<<<NB_SCAN, 256, 0, stream>>>(deg, local, bsum, nNodes);
    k_scan2<<<1, 256, 0, stream>>>(bsum, NB_SCAN);
    k_scan3<<<NB_SCAN, 256, 0, stream>>>(local, bsum, cursor, nNodes);
    k_scatter<<<NB_FLAT, 256, 0, stream>>>(src, dst, ea, cursor, rec, nEdges);
    k_wprep<<<(WP_TOTAL + 255) / 256, 256, 0, stream>>>(lin_w, mw1, mw2, uw1, uw2, wpH, wpL);

    k_in<<<NB_T, 256, 0, stream>>>(x, wpH + OFF_IN, wpL + OFF_IN, lin_b, h, nNodes);
    k_pre<<<NB_T, 256, 0, stream>>>(h, wpH + OFF_PRE(0), wpL + OFF_PRE(0),
        mb1, Pb, Qb, nNodes);   // layer 0 only; layers 1-3 fused into k_upd

    for (int l = 0; l < 4; ++l) {
        const int lp = (l < 3) ? (l + 1) : 3;    // W1(l+1) for fused pre (unused l=3)
        k_edge<<<NB_EDGE, 256, 0, stream>>>(Pb, Qb, rec,
            mw1 + (size_t)l * 134 * 64 + 128 * 64,
            wpH + OFF_MW2(l), wpL + OFF_MW2(l), mb2 + l * 64, agg, nEdges);
        k_upd<<<NB_T, 256, 0, stream>>>(h, agg,
            wpH + OFF_UW1(l), wpL + OFF_UW1(l), ub1 + l * 64,
            wpH + OFF_UW2(l), wpL + OFF_UW2(l), ub2 + l * 64,
            wpH + OFF_PRE(lp), wpL + OFF_PRE(lp),
            (l < 3) ? (mb1 + (l + 1) * 64) : mb1,
            Pb, Qb, colsum, nNodes, (l == 3) ? 1 : 0, (l < 3) ? 1 : 0);
    }

    k_out<<<1, 64, 0, stream>>>(colsum, pw, pb, (float*)d_out, nNodes);
}